// Round 17
// baseline (182.851 us; speedup 1.0000x reference)
//
#include <hip/hip_runtime.h>
#include <math.h>

#define Bsz 1024
#define Din 512
#define Hdim 1024
#define Aact 64
#define MAXT 23   // max row-tiles across experts: 7 partial + 16
#define NXCD 8

// out layout (float32): option_probs[1024*8] | action_probs[1024*64] | term[1024] | opt_argmax[1024] | sel_action[1024]
#define OFF_ACT   8192
#define OFF_TERM  73728
#define OFF_OARG  74752
#define OFF_SACT  75776

// ---------------- threefry2x32-20, key (0,42), partitionable XOR-fold (verified R3-R16) ----------------
__device__ __forceinline__ unsigned rotl32(unsigned x, int d){ return (x << d) | (x >> (32 - d)); }

__device__ __forceinline__ void threefry_042(unsigned& x0, unsigned& x1){
  const unsigned ks0 = 0u, ks1 = 42u, ks2 = 0x1BD11BDAu ^ 0u ^ 42u;
  x0 += ks0; x1 += ks1;
#define TFR(r) { x0 += x1; x1 = rotl32(x1, r); x1 ^= x0; }
  TFR(13) TFR(15) TFR(26) TFR(6)  x0 += ks1; x1 += ks2 + 1u;
  TFR(17) TFR(29) TFR(16) TFR(24) x0 += ks2; x1 += ks0 + 2u;
  TFR(13) TFR(15) TFR(26) TFR(6)  x0 += ks0; x1 += ks1 + 3u;
  TFR(17) TFR(29) TFR(16) TFR(24) x0 += ks1; x1 += ks2 + 4u;
  TFR(13) TFR(15) TFR(26) TFR(6)  x0 += ks2; x1 += ks0 + 5u;
#undef TFR
}

__device__ __forceinline__ float gumbel_at(int idx){
  unsigned x0 = 0u, x1 = (unsigned)idx;
  threefry_042(x0, x1);
  unsigned bits = x0 ^ x1;
  float f = __uint_as_float((bits >> 9) | 0x3F800000u) - 1.0f;
  float u = fmaxf(f, 1.1754944e-38f);
  return -logf(-logf(u));
}

// ---------------- 64x64 tile GEMM, 4 waves in-block split-K x GLOBAL split-K x2, 8x8/thread ----------
// R17 = R16's verified GEMM (raw sums, kb-encoded dst) + FOLDA variant: A-tile load folds
// relu(A + A2 + abias[rowexp[row]]) inline (consumes L1's split-K pair without a reduce kernel).
// No occupancy hints (R6/7/9: forced hints spill).
template<bool GATHER, bool DENSE, bool FOLDA>
__global__ __launch_bounds__(256)
void gemm_splitk(const float* __restrict__ A, int lda,
                 const float* __restrict__ W0, const float* __restrict__ W1,
                 long long wstride,
                 float* __restrict__ C0, float* __restrict__ C1,
                 float* __restrict__ P0, float* __restrict__ P1,
                 int N, int K,
                 const int* __restrict__ order, const int* __restrict__ offsets,
                 const int* __restrict__ tlist,
                 const float* __restrict__ A2, const float* __restrict__ abias,
                 const int* __restrict__ rowexp)
{
  const float* W; float* dst;
  int mbase, r1, n0, kb;
  if (DENSE){
    const int bid = (int)(blockIdx.x + 16u*blockIdx.y + 256u*blockIdx.z);  // 0..1023
    const int wf = (bid & 7) * 128 + (bid >> 3);                           // bijective XCD swizzle
    const int ny = wf & 15, mx = (wf >> 4) & 15, zz = wf >> 8;             // zz 0..3
    const int net = zz & 1; kb = zz >> 1;
    mbase = mx * 64; r1 = Bsz; n0 = ny * 64;
    W = net ? W1 : W0;
    dst = kb ? (net ? P1 : P0) : (net ? C1 : C0);
  } else {
    const int bid = (int)(blockIdx.x + 23u*blockIdx.y + 368u*blockIdx.z);  // 0..735
    const int wf = (bid & 7) * 92 + (bid >> 3);                            // bijective (736=92*8)
    kb = wf / 368; const int rem = wf - kb * 368;
    const int i = rem >> 4;
    if (i >= tlist[0]) return;
    const int o = tlist[1 + 2*i];
    mbase = tlist[2 + 2*i];
    r1 = offsets[o + 1];
    n0 = (rem & 15) * 64;
    W = W0 + (long long)o * wstride;
    dst = kb ? P0 : C0;
  }

  __shared__ float lds[8576];   // staging: 4 waves x 1024; reduce: 2 x 4288 (overlaid after K-loop)

  const int tid = threadIdx.x;
  const int wv = tid >> 6, lane = tid & 63;
  const int ty = lane >> 3, tx = lane & 7;
  const int KC = K >> 3, NT = KC >> 3;      // K / (4 waves x 2 kb); 8-k sub-tiles
  const int k0 = (kb * 4 + wv) * KC;
  const int bkr = lane >> 4;                // B: base k-row (0..3)
  const int bnc = (lane & 15) * 4;          // B: column quad

  int grow = mbase + lane;
  int arow = grow < r1 ? grow : mbase;
  if (GATHER) arow = order[arow];
  const float* Ap = A + (long long)arow * lda + k0;
  const float* Ap2 = nullptr; const float* Bp = nullptr;
  if (FOLDA){
    Ap2 = A2 + (long long)arow * lda + k0;
    Bp  = abias + (long long)rowexp[arow] * lda + k0;
  }
  const float* Wp = W + (long long)k0 * N + n0 + bnc;

  float* myst = lds + wv * 1024;            // [As 8x64 | Bs 8x64]

  float acc[8][8];
#pragma unroll
  for (int i = 0; i < 8; i++)
#pragma unroll
    for (int j = 0; j < 8; j++) acc[i][j] = 0.f;

  float4 a4[2], b4[2];

#define LOADT(it) {                                                          \
    const float* ap = Ap + (it) * 8;                                         \
    a4[0] = *(const float4*)(ap + 0);  a4[1] = *(const float4*)(ap + 4);     \
    if (FOLDA){                                                              \
      const float* aq = Ap2 + (it) * 8;                                      \
      const float* bq = Bp + (it) * 8;                                       \
      float4 y0 = *(const float4*)(aq + 0), y1 = *(const float4*)(aq + 4);   \
      float4 z0 = *(const float4*)(bq + 0), z1 = *(const float4*)(bq + 4);   \
      a4[0].x = fmaxf(a4[0].x + y0.x + z0.x, 0.f);                           \
      a4[0].y = fmaxf(a4[0].y + y0.y + z0.y, 0.f);                           \
      a4[0].z = fmaxf(a4[0].z + y0.z + z0.z, 0.f);                           \
      a4[0].w = fmaxf(a4[0].w + y0.w + z0.w, 0.f);                           \
      a4[1].x = fmaxf(a4[1].x + y1.x + z1.x, 0.f);                           \
      a4[1].y = fmaxf(a4[1].y + y1.y + z1.y, 0.f);                           \
      a4[1].z = fmaxf(a4[1].z + y1.z + z1.z, 0.f);                           \
      a4[1].w = fmaxf(a4[1].w + y1.w + z1.w, 0.f);                           \
    }                                                                        \
    const float* wp = Wp + (long long)((it) * 8 + bkr) * N;                  \
    b4[0] = *(const float4*)(wp);                                            \
    b4[1] = *(const float4*)(wp + (long long)4 * N); }

#define STORET() {                                                           \
    float* As = myst;                                                        \
    float* Bs = myst + 512;                                                  \
    _Pragma("unroll")                                                        \
    for (int q = 0; q < 2; q++){                                             \
      As[(q*4 + 0)*64 + lane] = a4[q].x;                                     \
      As[(q*4 + 1)*64 + lane] = a4[q].y;                                     \
      As[(q*4 + 2)*64 + lane] = a4[q].z;                                     \
      As[(q*4 + 3)*64 + lane] = a4[q].w; }                                   \
    _Pragma("unroll")                                                        \
    for (int r = 0; r < 2; r++)                                              \
      *(float4*)(Bs + (bkr + r*4)*64 + bnc) = b4[r]; }

  LOADT(0); STORET(); LOADT(1);
  asm volatile("s_waitcnt lgkmcnt(0)" ::: "memory");

  for (int it = 0; it < NT; ++it){
    const float* As = myst;
    const float* Bs = myst + 512;
#pragma unroll
    for (int kk = 0; kk < 8; ++kk){
      float4 av0 = *(const float4*)(As + kk*64 + ty*8);
      float4 av1 = *(const float4*)(As + kk*64 + ty*8 + 4);
      float4 bv0 = *(const float4*)(Bs + kk*64 + tx*8);
      float4 bv1 = *(const float4*)(Bs + kk*64 + tx*8 + 4);
      float a[8] = {av0.x,av0.y,av0.z,av0.w,av1.x,av1.y,av1.z,av1.w};
      float b[8] = {bv0.x,bv0.y,bv0.z,bv0.w,bv1.x,bv1.y,bv1.z,bv1.w};
#pragma unroll
      for (int i = 0; i < 8; i++)
#pragma unroll
        for (int j = 0; j < 8; j++) acc[i][j] = fmaf(a[i], b[j], acc[i][j]);
    }
    if (it + 1 < NT){
      asm volatile("s_waitcnt lgkmcnt(0)" ::: "memory");  // reads retired before overwrite
      STORET();                                           // (compiler inserts vmcnt for a4/b4)
      if (it + 2 < NT) LOADT(it + 2);
      asm volatile("s_waitcnt lgkmcnt(0)" ::: "memory");  // stores landed before next compute
    }
  }
#undef LOADT
#undef STORET

  // ---- log-tree cross-wave reduce: 4 -> 2 -> 1 (stride 67, proven 0-conflict R10-R16) ----
#define RWRITE(w) { float* r = lds + (w) * 4288 + lane * 67;                 \
    _Pragma("unroll")                                                        \
    for (int i = 0; i < 8; i++)                                              \
      _Pragma("unroll")                                                      \
      for (int j = 0; j < 8; j++) r[i*8 + j] = acc[i][j]; }
#define RADD(w) { const float* r = lds + (w) * 4288 + lane * 67;             \
    _Pragma("unroll")                                                        \
    for (int i = 0; i < 8; i++)                                              \
      _Pragma("unroll")                                                      \
      for (int j = 0; j < 8; j++) acc[i][j] += r[i*8 + j]; }

  __syncthreads();
  if (wv == 2 || wv == 3) RWRITE(wv - 2);
  __syncthreads();
  if (wv < 2)  RADD(wv);
  __syncthreads();
  if (wv == 1) RWRITE(0);
  __syncthreads();
  if (wv == 0){
    RADD(0);
#pragma unroll
    for (int i = 0; i < 8; i++){
      int row = mbase + ty*8 + i;
      if (row < r1){
        float* p = dst + (long long)row * N + n0 + tx*8;
        float4 v0, v1;
        v0.x = acc[i][0]; v0.y = acc[i][1]; v0.z = acc[i][2]; v0.w = acc[i][3];
        v1.x = acc[i][4]; v1.y = acc[i][5]; v1.z = acc[i][6]; v1.w = acc[i][7];
        *(float4*)p = v0; *(float4*)(p + 4) = v1;
      }
    }
  }
#undef RWRITE
#undef RADD
}

// ---------------- per-row head: folds relu(ba+bb+ob1) / relu(bc+bd+tb1) inline ----------------
__global__ __launch_bounds__(256)
void head_kernel(const float* __restrict__ ba, const float* __restrict__ bb,
                 const float* __restrict__ bc, const float* __restrict__ bd,
                 const float* __restrict__ ob1, const float* __restrict__ tb1,
                 const float* __restrict__ ow2, const float* __restrict__ ob2,
                 const float* __restrict__ tw2, const float* __restrict__ tb2,
                 float* __restrict__ out, int* __restrict__ sel)
{
  const int b = blockIdx.x;
  const int t = threadIdx.x;
  const long long rb = (long long)b * Hdim;

  float acc[8] = {}; float accT = 0.f;
  for (int k = t; k < Hdim; k += 256){
    float hv = fmaxf(ba[rb + k] + bb[rb + k] + ob1[k], 0.f);
    float tv = fmaxf(bc[rb + k] + bd[rb + k] + tb1[k], 0.f);
    const float* w = ow2 + k * 8;
#pragma unroll
    for (int o2 = 0; o2 < 8; ++o2) acc[o2] += hv * w[o2];
    accT += tv * tw2[k];
  }
#pragma unroll
  for (int o2 = 0; o2 < 8; ++o2)
    for (int off = 32; off; off >>= 1) acc[o2] += __shfl_down(acc[o2], off);
  for (int off = 32; off; off >>= 1) accT += __shfl_down(accT, off);

  __shared__ float wred[4][9];
  __shared__ float logits[8];
  __shared__ float gum[8];
  const int wave = t >> 6, lane = t & 63;
  if (lane == 0){
#pragma unroll
    for (int o2 = 0; o2 < 8; ++o2) wred[wave][o2] = acc[o2];
    wred[wave][8] = accT;
  }
  __syncthreads();
  if (t < 9){
    float s = wred[0][t] + wred[1][t] + wred[2][t] + wred[3][t];
    if (t < 8) logits[t] = s + ob2[t];
    else       out[OFF_TERM + b] = 1.f / (1.f + expf(-(s + tb2[0])));
  }
  __syncthreads();
  if (t < 8) gum[t] = logits[t] + gumbel_at(b * 8 + t);
  __syncthreads();
  if (t == 0){
    float m = logits[0]; int am = 0;
#pragma unroll
    for (int o2 = 1; o2 < 8; ++o2) if (logits[o2] > m){ m = logits[o2]; am = o2; }
    float p[8]; float s = 0.f;
#pragma unroll
    for (int o2 = 0; o2 < 8; ++o2){ p[o2] = expf(logits[o2] - m); s += p[o2]; }
    float inv = 1.f / s;
#pragma unroll
    for (int o2 = 0; o2 < 8; ++o2) out[b * 8 + o2] = p[o2] * inv;
    out[OFF_OARG + b] = (float)am;
    float gm = gum[0]; int gs = 0;
#pragma unroll
    for (int o2 = 1; o2 < 8; ++o2) if (gum[o2] > gm){ gm = gum[o2]; gs = o2; }
    sel[b] = gs;
  }
}

// ---------------- routing: bucket by expert + row-tile list + per-row expert index ----------------
__global__ void route_kernel(const int* __restrict__ sel, int* __restrict__ order,
                             int* __restrict__ offsets, int* __restrict__ tlist,
                             int* __restrict__ rowexp)
{
  __shared__ int cnt[8];
  __shared__ int base[8];
  const int t = threadIdx.x;
  if (t < 8) cnt[t] = 0;
  __syncthreads();
  const int s = sel[t];
  atomicAdd(&cnt[s], 1);
  __syncthreads();
  if (t == 0){
    int a = 0;
    for (int o = 0; o < 8; ++o){ offsets[o] = a; base[o] = a; a += cnt[o]; }
    offsets[8] = a;
    int nt = 0;
    for (int o = 0; o < 8; ++o)
      for (int mb = offsets[o]; mb < offsets[o] + cnt[o]; mb += 64){
        tlist[1 + 2*nt] = o; tlist[2 + 2*nt] = mb; ++nt;
      }
    tlist[0] = nt;
  }
  __syncthreads();
  // per permuted-row expert index (offsets ready after the barrier)
  {
    int o = 0;
#pragma unroll
    for (int i = 1; i < 8; ++i) if (offsets[i] <= t) o = i;
    rowexp[t] = o;
  }
  const int pos = atomicAdd(&base[s], 1);
  order[pos] = t;   // permutation within an expert is nondeterministic; outputs don't depend on it
}

// ---------------- per-row output head: folds relu(ba+bb+abh[o]) inline ----------------
__global__ __launch_bounds__(256)
void expert_out_kernel(const float* __restrict__ ba, const float* __restrict__ bb,
                       const float* __restrict__ abh,
                       const float* __restrict__ awo, const float* __restrict__ abo,
                       const int* __restrict__ order, const int* __restrict__ offsets,
                       float* __restrict__ out)
{
  const int r = blockIdx.x;
  int o = 0;
#pragma unroll
  for (int i = 1; i < 8; ++i) if (offsets[i] <= r) o = i;
  const int t = threadIdx.x;
  const int a = t & 63, kg = t >> 6;
  const long long rb = (long long)r * Hdim;
  const float* ab = abh + (long long)o * Hdim;
  const float* W = awo + (long long)o * Hdim * Aact;
  float acc = 0.f;
  const int k0 = kg * 256;
  for (int k = k0; k < k0 + 256; ++k){
    float hv = fmaxf(ba[rb + k] + bb[rb + k] + ab[k], 0.f);
    acc += hv * W[k * Aact + a];
  }
  __shared__ float redm[4][64];
  redm[kg][a] = acc;
  __syncthreads();
  if (t < 64){
    float q = redm[0][a] + redm[1][a] + redm[2][a] + redm[3][a] + abo[o * Aact + a];
    float m = q;
#pragma unroll
    for (int off = 32; off; off >>= 1) m = fmaxf(m, __shfl_xor(m, off));
    float e = expf(q - m);
    float s = e;
#pragma unroll
    for (int off = 32; off; off >>= 1) s += __shfl_xor(s, off);
    const int b = order[r];
    out[OFF_ACT + b * Aact + a] = e / s;
    unsigned long long msk = __ballot(q == m);
    if (a == 0) out[OFF_SACT + b] = (float)__builtin_ctzll(msk);
  }
}

extern "C" void kernel_launch(void* const* d_in, const int* in_sizes, int n_in,
                              void* d_out, int out_size, void* d_ws, size_t ws_size,
                              hipStream_t stream)
{
  (void)in_sizes; (void)n_in; (void)out_size; (void)ws_size;
  const float* state = (const float*)d_in[0];
  const float* ow1   = (const float*)d_in[1];
  const float* ob1   = (const float*)d_in[2];
  const float* ow2   = (const float*)d_in[3];
  const float* ob2   = (const float*)d_in[4];
  const float* aw1   = (const float*)d_in[5];
  const float* ab1   = (const float*)d_in[6];
  const float* awh   = (const float*)d_in[7];
  const float* abh   = (const float*)d_in[8];
  const float* awo   = (const float*)d_in[9];
  const float* abo   = (const float*)d_in[10];
  const float* tw1   = (const float*)d_in[11];
  const float* tb1   = (const float*)d_in[12];
  const float* tw2   = (const float*)d_in[13];
  const float* tb2   = (const float*)d_in[14];
  float* out = (float*)d_out;

  // 4 x [1024][1024] split-K pair buffers, reused across stages (stream-ordered):
  // dense: opt={ba,bb}, term={bc,bd} -> head consumes all 4
  // L1 -> {bc,bd} (term pair dead after head); L2 reads fold(bc,bd,ab1) -> {ba,bb}
  // expert_out reads fold(ba,bb,abh)
  float* ba = (float*)d_ws;
  float* bb = ba + (long long)Bsz * Hdim;
  float* bc = bb + (long long)Bsz * Hdim;
  float* bd = bc + (long long)Bsz * Hdim;
  int* sel     = (int*)(bd + (long long)Bsz * Hdim);
  int* order   = sel + Bsz;
  int* offsets = order + Bsz;
  int* tlist   = offsets + 9;           // [ntiles | (expert,mbase) * MAXT]
  int* rowexp  = tlist + 1 + 2 * MAXT;

  // 1. dense pair raw sums: opt kb0->ba kb1->bb; term kb0->bc kb1->bd
  gemm_splitk<false,true,false><<<dim3(16,16,4), 256, 0, stream>>>(
      state, Din, ow1, tw1, 0, ba, bc, bb, bd, Hdim, Din,
      nullptr, nullptr, nullptr, nullptr, nullptr, nullptr);
  // 2. heads (folds dense sums+bias+relu): opt softmax/argmax, gumbel sel, termination
  head_kernel<<<dim3(Bsz), 256, 0, stream>>>(
      ba, bb, bc, bd, ob1, tb1, ow2, ob2, tw2, tb2, out, sel);
  // 3. bucket samples by expert + tile list + per-row expert index
  route_kernel<<<dim3(1), 1024, 0, stream>>>(sel, order, offsets, tlist, rowexp);
  // 4. expert L1 raw sums (gather state rows): kb0->bc, kb1->bd
  gemm_splitk<true,false,false><<<dim3(MAXT,16,2), 256, 0, stream>>>(
      state, Din, aw1, nullptr, (long long)Din*Hdim, bc, nullptr, bd, nullptr,
      Hdim, Din, order, offsets, tlist, nullptr, nullptr, nullptr);
  // 5. expert L2 raw sums (A = fold(bc,bd,ab1[rowexp])): kb0->ba, kb1->bb
  gemm_splitk<false,false,true><<<dim3(MAXT,16,2), 256, 0, stream>>>(
      bc, Hdim, awh, nullptr, (long long)Hdim*Hdim, ba, nullptr, bb, nullptr,
      Hdim, Hdim, nullptr, offsets, tlist, bd, ab1, rowexp);
  // 6. output head (folds L2 sums+bias+relu): q, action softmax, selected action
  expert_out_kernel<<<dim3(Bsz), 256, 0, stream>>>(
      ba, bb, abh, awo, abo, order, offsets, out);
}

// Round 18
// 167.391 us; speedup vs baseline: 1.0924x; 1.0924x over previous
//
#include <hip/hip_runtime.h>
#include <math.h>

#define Bsz 1024
#define Din 512
#define Hdim 1024
#define Aact 64
#define MAXT 23   // max row-tiles across experts: 7 partial + 16
#define NXCD 8

// out layout (float32): option_probs[1024*8] | action_probs[1024*64] | term[1024] | opt_argmax[1024] | sel_action[1024]
#define OFF_ACT   8192
#define OFF_TERM  73728
#define OFF_OARG  74752
#define OFF_SACT  75776

// ---------------- threefry2x32-20, key (0,42), partitionable XOR-fold (verified R3-R17) ----------------
__device__ __forceinline__ unsigned rotl32(unsigned x, int d){ return (x << d) | (x >> (32 - d)); }

__device__ __forceinline__ void threefry_042(unsigned& x0, unsigned& x1){
  const unsigned ks0 = 0u, ks1 = 42u, ks2 = 0x1BD11BDAu ^ 0u ^ 42u;
  x0 += ks0; x1 += ks1;
#define TFR(r) { x0 += x1; x1 = rotl32(x1, r); x1 ^= x0; }
  TFR(13) TFR(15) TFR(26) TFR(6)  x0 += ks1; x1 += ks2 + 1u;
  TFR(17) TFR(29) TFR(16) TFR(24) x0 += ks2; x1 += ks0 + 2u;
  TFR(13) TFR(15) TFR(26) TFR(6)  x0 += ks0; x1 += ks1 + 3u;
  TFR(17) TFR(29) TFR(16) TFR(24) x0 += ks1; x1 += ks2 + 4u;
  TFR(13) TFR(15) TFR(26) TFR(6)  x0 += ks2; x1 += ks0 + 5u;
#undef TFR
}

__device__ __forceinline__ float gumbel_at(int idx){
  unsigned x0 = 0u, x1 = (unsigned)idx;
  threefry_042(x0, x1);
  unsigned bits = x0 ^ x1;
  float f = __uint_as_float((bits >> 9) | 0x3F800000u) - 1.0f;
  float u = fmaxf(f, 1.1754944e-38f);
  return -logf(-logf(u));
}

// ---------------- 64x64 tile GEMM, 4 waves in-block split-K, 8x8/thread ----------------
// R18 = R15's proven kernel; RAW variant adds R16's verified global split-K x2 for grouped mode
// (kb from blockIdx.z, raw sums to C/P, bias+relu deferred to the consumer). The R17 FOLDA path
// (which slowed LOADT and perturbed codegen) is REMOVED. No occupancy hints (R6/7/9: hints spill).
template<bool GATHER, bool DENSE, bool RAW>
__global__ __launch_bounds__(256)
void gemm_splitk(const float* __restrict__ A, int lda,
                 const float* __restrict__ W0, const float* __restrict__ W1,
                 long long wstride,
                 const float* __restrict__ b0, const float* __restrict__ b1,
                 int bstride,
                 float* __restrict__ C0, float* __restrict__ C1,
                 float* __restrict__ P0,
                 int N, int K,
                 const int* __restrict__ order, const int* __restrict__ offsets,
                 const int* __restrict__ tlist)
{
  const float* W; const float* bias = nullptr; float* dst;
  int mbase, r1, n0, kb = 0;
  if (DENSE){
    const int bid = (int)(blockIdx.x + gridDim.x * (blockIdx.y + gridDim.y * blockIdx.z)); // 0..511
    const int wf = (bid % NXCD) * (512 / NXCD) + bid / NXCD;   // bijective XCD swizzle (512%8==0)
    const int ny = wf & 15, mx = (wf >> 4) & 15, z = wf >> 8;
    mbase = mx * 64; r1 = Bsz; n0 = ny * 64;
    W = z ? W1 : W0; bias = z ? b1 : b0; dst = z ? C1 : C0;
  } else if (!RAW){
    const int bid = (int)(blockIdx.x + gridDim.x * blockIdx.y); // 368 = 46*8, bijective
    const int wf = (bid % NXCD) * ((MAXT * 16) / NXCD) + bid / NXCD;
    const int i = wf >> 4;
    if (i >= tlist[0]) return;
    const int o = tlist[1 + 2*i];
    mbase = tlist[2 + 2*i];
    r1 = offsets[o + 1];
    n0 = (wf & 15) * 64;
    W = W0 + (long long)o * wstride; bias = b0 + o * bstride; dst = C0;
  } else {
    const int bid = (int)(blockIdx.x + 23u*blockIdx.y + 368u*blockIdx.z);  // 0..735
    const int wf = (bid & 7) * 92 + (bid >> 3);                            // bijective (736=92*8)
    kb = wf / 368; const int rem = wf - kb * 368;
    const int i = rem >> 4;
    if (i >= tlist[0]) return;
    const int o = tlist[1 + 2*i];
    mbase = tlist[2 + 2*i];
    r1 = offsets[o + 1];
    n0 = (rem & 15) * 64;
    W = W0 + (long long)o * wstride;
    dst = kb ? P0 : C0;
  }

  __shared__ float lds[8576];   // staging: 4 waves x 1024; reduce: 2 x 4288 (overlaid after K-loop)

  const int tid = threadIdx.x;
  const int wv = tid >> 6, lane = tid & 63;
  const int ty = lane >> 3, tx = lane & 7;
  const int KC = RAW ? (K >> 3) : (K >> 2);  // RAW: K / (4 waves x 2 kb)
  const int NT = KC >> 3;                    // 8-k sub-tiles
  const int k0 = (RAW ? (kb * 4 + wv) : wv) * KC;
  const int bkr = lane >> 4;                // B: base k-row (0..3)
  const int bnc = (lane & 15) * 4;          // B: column quad

  int grow = mbase + lane;
  int arow = grow < r1 ? grow : mbase;
  if (GATHER) arow = order[arow];
  const float* Ap = A + (long long)arow * lda + k0;
  const float* Wp = W + (long long)k0 * N + n0 + bnc;

  float* myst = lds + wv * 1024;            // [As 8x64 | Bs 8x64]

  float acc[8][8];
#pragma unroll
  for (int i = 0; i < 8; i++)
#pragma unroll
    for (int j = 0; j < 8; j++) acc[i][j] = 0.f;

  float4 a4[2], b4[2];

#define LOADT(it) {                                                          \
    const float* ap = Ap + (it) * 8;                                         \
    a4[0] = *(const float4*)(ap + 0);  a4[1] = *(const float4*)(ap + 4);     \
    const float* wp = Wp + (long long)((it) * 8 + bkr) * N;                  \
    b4[0] = *(const float4*)(wp);                                            \
    b4[1] = *(const float4*)(wp + (long long)4 * N); }

#define STORET() {                                                           \
    float* As = myst;                                                        \
    float* Bs = myst + 512;                                                  \
    _Pragma("unroll")                                                        \
    for (int q = 0; q < 2; q++){                                             \
      As[(q*4 + 0)*64 + lane] = a4[q].x;                                     \
      As[(q*4 + 1)*64 + lane] = a4[q].y;                                     \
      As[(q*4 + 2)*64 + lane] = a4[q].z;                                     \
      As[(q*4 + 3)*64 + lane] = a4[q].w; }                                   \
    _Pragma("unroll")                                                        \
    for (int r = 0; r < 2; r++)                                              \
      *(float4*)(Bs + (bkr + r*4)*64 + bnc) = b4[r]; }

  LOADT(0); STORET(); LOADT(1);
  asm volatile("s_waitcnt lgkmcnt(0)" ::: "memory");

  for (int it = 0; it < NT; ++it){
    const float* As = myst;
    const float* Bs = myst + 512;
#pragma unroll
    for (int kk = 0; kk < 8; ++kk){
      float4 av0 = *(const float4*)(As + kk*64 + ty*8);
      float4 av1 = *(const float4*)(As + kk*64 + ty*8 + 4);
      float4 bv0 = *(const float4*)(Bs + kk*64 + tx*8);
      float4 bv1 = *(const float4*)(Bs + kk*64 + tx*8 + 4);
      float a[8] = {av0.x,av0.y,av0.z,av0.w,av1.x,av1.y,av1.z,av1.w};
      float b[8] = {bv0.x,bv0.y,bv0.z,bv0.w,bv1.x,bv1.y,bv1.z,bv1.w};
#pragma unroll
      for (int i = 0; i < 8; i++)
#pragma unroll
        for (int j = 0; j < 8; j++) acc[i][j] = fmaf(a[i], b[j], acc[i][j]);
    }
    if (it + 1 < NT){
      asm volatile("s_waitcnt lgkmcnt(0)" ::: "memory");  // reads retired before overwrite
      STORET();                                           // (compiler inserts vmcnt for a4/b4)
      if (it + 2 < NT) LOADT(it + 2);
      asm volatile("s_waitcnt lgkmcnt(0)" ::: "memory");  // stores landed before next compute
    }
  }
#undef LOADT
#undef STORET

  // ---- log-tree cross-wave reduce: 4 -> 2 -> 1 (stride 67, proven 0-conflict R10-R17) ----
#define RWRITE(w) { float* r = lds + (w) * 4288 + lane * 67;                 \
    _Pragma("unroll")                                                        \
    for (int i = 0; i < 8; i++)                                              \
      _Pragma("unroll")                                                      \
      for (int j = 0; j < 8; j++) r[i*8 + j] = acc[i][j]; }
#define RADD(w) { const float* r = lds + (w) * 4288 + lane * 67;             \
    _Pragma("unroll")                                                        \
    for (int i = 0; i < 8; i++)                                              \
      _Pragma("unroll")                                                      \
      for (int j = 0; j < 8; j++) acc[i][j] += r[i*8 + j]; }

  __syncthreads();
  if (wv == 2 || wv == 3) RWRITE(wv - 2);
  __syncthreads();
  if (wv < 2)  RADD(wv);
  __syncthreads();
  if (wv == 1) RWRITE(0);
  __syncthreads();
  if (wv == 0){
    RADD(0);
#pragma unroll
    for (int i = 0; i < 8; i++){
      int row = mbase + ty*8 + i;
      if (row < r1){
        float* p = dst + (long long)row * N + n0 + tx*8;
        if (RAW){
          float4 v0, v1;
          v0.x = acc[i][0]; v0.y = acc[i][1]; v0.z = acc[i][2]; v0.w = acc[i][3];
          v1.x = acc[i][4]; v1.y = acc[i][5]; v1.z = acc[i][6]; v1.w = acc[i][7];
          *(float4*)p = v0; *(float4*)(p + 4) = v1;
        } else {
#pragma unroll
          for (int j = 0; j < 8; j++)
            p[j] = fmaxf(acc[i][j] + bias[n0 + tx*8 + j], 0.0f);
        }
      }
    }
  }
#undef RWRITE
#undef RADD
}

// ---------------- per-row head: opt logits + softmax + argmax + gumbel sel + termination ----------------
__global__ __launch_bounds__(256)
void head_kernel(const float* __restrict__ h1, const float* __restrict__ th,
                 const float* __restrict__ ow2, const float* __restrict__ ob2,
                 const float* __restrict__ tw2, const float* __restrict__ tb2,
                 float* __restrict__ out, int* __restrict__ sel)
{
  const int b = blockIdx.x;
  const int t = threadIdx.x;
  const float* hrow = h1 + b * Hdim;
  const float* trow = th + b * Hdim;

  float acc[8] = {}; float accT = 0.f;
  for (int k = t; k < Hdim; k += 256){
    float hv = hrow[k];
    const float* w = ow2 + k * 8;
#pragma unroll
    for (int o2 = 0; o2 < 8; ++o2) acc[o2] += hv * w[o2];
    accT += trow[k] * tw2[k];
  }
#pragma unroll
  for (int o2 = 0; o2 < 8; ++o2)
    for (int off = 32; off; off >>= 1) acc[o2] += __shfl_down(acc[o2], off);
  for (int off = 32; off; off >>= 1) accT += __shfl_down(accT, off);

  __shared__ float wred[4][9];
  __shared__ float logits[8];
  __shared__ float gum[8];
  const int wave = t >> 6, lane = t & 63;
  if (lane == 0){
#pragma unroll
    for (int o2 = 0; o2 < 8; ++o2) wred[wave][o2] = acc[o2];
    wred[wave][8] = accT;
  }
  __syncthreads();
  if (t < 9){
    float s = wred[0][t] + wred[1][t] + wred[2][t] + wred[3][t];
    if (t < 8) logits[t] = s + ob2[t];
    else       out[OFF_TERM + b] = 1.f / (1.f + expf(-(s + tb2[0])));
  }
  __syncthreads();
  if (t < 8) gum[t] = logits[t] + gumbel_at(b * 8 + t);
  __syncthreads();
  if (t == 0){
    float m = logits[0]; int am = 0;
#pragma unroll
    for (int o2 = 1; o2 < 8; ++o2) if (logits[o2] > m){ m = logits[o2]; am = o2; }
    float p[8]; float s = 0.f;
#pragma unroll
    for (int o2 = 0; o2 < 8; ++o2){ p[o2] = expf(logits[o2] - m); s += p[o2]; }
    float inv = 1.f / s;
#pragma unroll
    for (int o2 = 0; o2 < 8; ++o2) out[b * 8 + o2] = p[o2] * inv;
    out[OFF_OARG + b] = (float)am;
    float gm = gum[0]; int gs = 0;
#pragma unroll
    for (int o2 = 1; o2 < 8; ++o2) if (gum[o2] > gm){ gm = gum[o2]; gs = o2; }
    sel[b] = gs;
  }
}

// ---------------- routing: bucket samples by expert + emit row-tile list ----------------
__global__ void route_kernel(const int* __restrict__ sel, int* __restrict__ order,
                             int* __restrict__ offsets, int* __restrict__ tlist)
{
  __shared__ int cnt[8];
  __shared__ int base[8];
  const int t = threadIdx.x;
  if (t < 8) cnt[t] = 0;
  __syncthreads();
  const int s = sel[t];
  atomicAdd(&cnt[s], 1);
  __syncthreads();
  if (t == 0){
    int a = 0;
    for (int o = 0; o < 8; ++o){ offsets[o] = a; base[o] = a; a += cnt[o]; }
    offsets[8] = a;
    int nt = 0;
    for (int o = 0; o < 8; ++o)
      for (int mb = offsets[o]; mb < offsets[o] + cnt[o]; mb += 64){
        tlist[1 + 2*nt] = o; tlist[2 + 2*nt] = mb; ++nt;
      }
    tlist[0] = nt;
  }
  __syncthreads();
  const int pos = atomicAdd(&base[s], 1);
  order[pos] = t;   // permutation within an expert is nondeterministic; outputs don't depend on it
}

// ---------------- per-row output head: folds relu(ba+bb+abh[o]) inline (verified R17) ----------------
__global__ __launch_bounds__(256)
void expert_out_kernel(const float* __restrict__ ba, const float* __restrict__ bb,
                       const float* __restrict__ abh,
                       const float* __restrict__ awo, const float* __restrict__ abo,
                       const int* __restrict__ order, const int* __restrict__ offsets,
                       float* __restrict__ out)
{
  const int r = blockIdx.x;
  int o = 0;
#pragma unroll
  for (int i = 1; i < 8; ++i) if (offsets[i] <= r) o = i;
  const int t = threadIdx.x;
  const int a = t & 63, kg = t >> 6;
  const long long rb = (long long)r * Hdim;
  const float* ab = abh + (long long)o * Hdim;
  const float* W = awo + (long long)o * Hdim * Aact;
  float acc = 0.f;
  const int k0 = kg * 256;
  for (int k = k0; k < k0 + 256; ++k){
    float hv = fmaxf(ba[rb + k] + bb[rb + k] + ab[k], 0.f);
    acc += hv * W[k * Aact + a];
  }
  __shared__ float redm[4][64];
  redm[kg][a] = acc;
  __syncthreads();
  if (t < 64){
    float q = redm[0][a] + redm[1][a] + redm[2][a] + redm[3][a] + abo[o * Aact + a];
    float m = q;
#pragma unroll
    for (int off = 32; off; off >>= 1) m = fmaxf(m, __shfl_xor(m, off));
    float e = expf(q - m);
    float s = e;
#pragma unroll
    for (int off = 32; off; off >>= 1) s += __shfl_xor(s, off);
    const int b = order[r];
    out[OFF_ACT + b * Aact + a] = e / s;
    unsigned long long msk = __ballot(q == m);
    if (a == 0) out[OFF_SACT + b] = (float)__builtin_ctzll(msk);
  }
}

extern "C" void kernel_launch(void* const* d_in, const int* in_sizes, int n_in,
                              void* d_out, int out_size, void* d_ws, size_t ws_size,
                              hipStream_t stream)
{
  (void)in_sizes; (void)n_in; (void)out_size; (void)ws_size;
  const float* state = (const float*)d_in[0];
  const float* ow1   = (const float*)d_in[1];
  const float* ob1   = (const float*)d_in[2];
  const float* ow2   = (const float*)d_in[3];
  const float* ob2   = (const float*)d_in[4];
  const float* aw1   = (const float*)d_in[5];
  const float* ab1   = (const float*)d_in[6];
  const float* awh   = (const float*)d_in[7];
  const float* abh   = (const float*)d_in[8];
  const float* awo   = (const float*)d_in[9];
  const float* abo   = (const float*)d_in[10];
  const float* tw1   = (const float*)d_in[11];
  const float* tb1   = (const float*)d_in[12];
  const float* tw2   = (const float*)d_in[13];
  const float* tb2   = (const float*)d_in[14];
  float* out = (float*)d_out;

  float* h1 = (float*)d_ws;             // opt hidden -> expert L1 out (relu'd, permuted rows)
  float* h2 = h1 + (long long)Bsz * Hdim;  // term hidden -> L2 raw kb0
  float* pd = h2 + (long long)Bsz * Hdim;  // L2 raw kb1
  int* sel     = (int*)(pd + (long long)Bsz * Hdim);
  int* order   = sel + Bsz;
  int* offsets = order + Bsz;
  int* tlist   = offsets + 9;           // [ntiles | (expert,mbase) * MAXT]

  // 1. dense pair (opt+term hidden, bias+relu epilogue): z=0 -> h1, z=1 -> h2
  gemm_splitk<false,true,false><<<dim3(16,16,2), 256, 0, stream>>>(
      state, Din, ow1, tw1, 0, ob1, tb1, 0, h1, h2, nullptr,
      Hdim, Din, nullptr, nullptr, nullptr);
  // 2. heads: opt softmax/argmax, gumbel categorical sel, termination sigmoid
  head_kernel<<<dim3(Bsz), 256, 0, stream>>>(h1, h2, ow2, ob2, tw2, tb2, out, sel);
  // 3. bucket samples by expert + tile list
  route_kernel<<<dim3(1), 1024, 0, stream>>>(sel, order, offsets, tlist);
  // 4. expert L1 (gather state rows, bias+relu epilogue): h1[r] = relu(state[order[r]] @ aw1[o] + ab1[o])
  gemm_splitk<true,false,false><<<dim3(MAXT,16), 256, 0, stream>>>(
      state, Din, aw1, nullptr, (long long)Din*Hdim, ab1, nullptr, Hdim,
      h1, nullptr, nullptr, Hdim, Din, order, offsets, tlist);
  // 5. expert L2 raw sums, global split-K x2: kb0 -> h2, kb1 -> pd
  gemm_splitk<false,false,true><<<dim3(MAXT,16,2), 256, 0, stream>>>(
      h1, Hdim, awh, nullptr, (long long)Hdim*Hdim, nullptr, nullptr, 0,
      h2, nullptr, pd, Hdim, Hdim, nullptr, offsets, tlist);
  // 6. output head (folds h2+pd+abh[o] + relu): q, action softmax, selected action
  expert_out_kernel<<<dim3(Bsz), 256, 0, stream>>>(
      h2, pd, abh, awo, abo, order, offsets, out);
}

// Round 19
// 159.107 us; speedup vs baseline: 1.1492x; 1.0521x over previous
//
#include <hip/hip_runtime.h>
#include <math.h>

#define Bsz 1024
#define Din 512
#define Hdim 1024
#define Aact 64
#define MAXT 23   // max row-tiles across experts: 7 partial + 16
#define NXCD 8

// out layout (float32): option_probs[1024*8] | action_probs[1024*64] | term[1024] | opt_argmax[1024] | sel_action[1024]
#define OFF_ACT   8192
#define OFF_TERM  73728
#define OFF_OARG  74752
#define OFF_SACT  75776

// ---------------- threefry2x32-20, key (0,42), partitionable XOR-fold (verified R3-R18) ----------------
__device__ __forceinline__ unsigned rotl32(unsigned x, int d){ return (x << d) | (x >> (32 - d)); }

__device__ __forceinline__ void threefry_042(unsigned& x0, unsigned& x1){
  const unsigned ks0 = 0u, ks1 = 42u, ks2 = 0x1BD11BDAu ^ 0u ^ 42u;
  x0 += ks0; x1 += ks1;
#define TFR(r) { x0 += x1; x1 = rotl32(x1, r); x1 ^= x0; }
  TFR(13) TFR(15) TFR(26) TFR(6)  x0 += ks1; x1 += ks2 + 1u;
  TFR(17) TFR(29) TFR(16) TFR(24) x0 += ks2; x1 += ks0 + 2u;
  TFR(13) TFR(15) TFR(26) TFR(6)  x0 += ks0; x1 += ks1 + 3u;
  TFR(17) TFR(29) TFR(16) TFR(24) x0 += ks1; x1 += ks2 + 4u;
  TFR(13) TFR(15) TFR(26) TFR(6)  x0 += ks2; x1 += ks0 + 5u;
#undef TFR
}

__device__ __forceinline__ float gumbel_at(int idx){
  unsigned x0 = 0u, x1 = (unsigned)idx;
  threefry_042(x0, x1);
  unsigned bits = x0 ^ x1;
  float f = __uint_as_float((bits >> 9) | 0x3F800000u) - 1.0f;
  float u = fmaxf(f, 1.1754944e-38f);
  return -logf(-logf(u));
}

// ---------------- 64x64 tile GEMM, 4 waves in-block split-K, 8x8/thread ----------------
// R19: grouped mode = R15 verbatim (bias+relu epilogue). Dense mode = R16's verified RAW
// global split-K x2 (kb via blockIdx.z, raw sums; bias+relu folded into head_kernel).
// Two instantiations only. No occupancy hints (R6/7/9: forced hints spill).
template<bool GATHER, bool DENSE>
__global__ __launch_bounds__(256)
void gemm_splitk(const float* __restrict__ A, int lda,
                 const float* __restrict__ W0, const float* __restrict__ W1,
                 long long wstride,
                 const float* __restrict__ b0, const float* __restrict__ b1,
                 int bstride,
                 float* __restrict__ C0, float* __restrict__ C1,
                 float* __restrict__ P0, float* __restrict__ P1,
                 int N, int K,
                 const int* __restrict__ order, const int* __restrict__ offsets,
                 const int* __restrict__ tlist)
{
  const float* W; const float* bias = nullptr; float* dst;
  int mbase, r1, n0, kb = 0;
  if (DENSE){
    const int bid = (int)(blockIdx.x + 16u*blockIdx.y + 256u*blockIdx.z);  // 0..1023
    const int wf = (bid & 7) * 128 + (bid >> 3);                           // bijective XCD swizzle
    const int ny = wf & 15, mx = (wf >> 4) & 15, zz = wf >> 8;             // zz 0..3
    const int net = zz & 1; kb = zz >> 1;
    mbase = mx * 64; r1 = Bsz; n0 = ny * 64;
    W = net ? W1 : W0;
    dst = kb ? (net ? P1 : P0) : (net ? C1 : C0);
  } else {
    const int bid = (int)(blockIdx.x + gridDim.x * blockIdx.y); // 368 = 46*8, bijective
    const int wf = (bid % NXCD) * ((MAXT * 16) / NXCD) + bid / NXCD;
    const int i = wf >> 4;
    if (i >= tlist[0]) return;
    const int o = tlist[1 + 2*i];
    mbase = tlist[2 + 2*i];
    r1 = offsets[o + 1];
    n0 = (wf & 15) * 64;
    W = W0 + (long long)o * wstride; bias = b0 + o * bstride; dst = C0;
  }

  __shared__ float lds[8576];   // staging: 4 waves x 1024; reduce: 2 x 4288 (overlaid after K-loop)

  const int tid = threadIdx.x;
  const int wv = tid >> 6, lane = tid & 63;
  const int ty = lane >> 3, tx = lane & 7;
  const int KC = DENSE ? (K >> 3) : (K >> 2);  // dense: K / (4 waves x 2 kb)
  const int NT = KC >> 3;                      // 8-k sub-tiles
  const int k0 = (DENSE ? (kb * 4 + wv) : wv) * KC;
  const int bkr = lane >> 4;                // B: base k-row (0..3)
  const int bnc = (lane & 15) * 4;          // B: column quad

  int grow = mbase + lane;
  int arow = grow < r1 ? grow : mbase;
  if (GATHER) arow = order[arow];
  const float* Ap = A + (long long)arow * lda + k0;
  const float* Wp = W + (long long)k0 * N + n0 + bnc;

  float* myst = lds + wv * 1024;            // [As 8x64 | Bs 8x64]

  float acc[8][8];
#pragma unroll
  for (int i = 0; i < 8; i++)
#pragma unroll
    for (int j = 0; j < 8; j++) acc[i][j] = 0.f;

  float4 a4[2], b4[2];

#define LOADT(it) {                                                          \
    const float* ap = Ap + (it) * 8;                                         \
    a4[0] = *(const float4*)(ap + 0);  a4[1] = *(const float4*)(ap + 4);     \
    const float* wp = Wp + (long long)((it) * 8 + bkr) * N;                  \
    b4[0] = *(const float4*)(wp);                                            \
    b4[1] = *(const float4*)(wp + (long long)4 * N); }

#define STORET() {                                                           \
    float* As = myst;                                                        \
    float* Bs = myst + 512;                                                  \
    _Pragma("unroll")                                                        \
    for (int q = 0; q < 2; q++){                                             \
      As[(q*4 + 0)*64 + lane] = a4[q].x;                                     \
      As[(q*4 + 1)*64 + lane] = a4[q].y;                                     \
      As[(q*4 + 2)*64 + lane] = a4[q].z;                                     \
      As[(q*4 + 3)*64 + lane] = a4[q].w; }                                   \
    _Pragma("unroll")                                                        \
    for (int r = 0; r < 2; r++)                                              \
      *(float4*)(Bs + (bkr + r*4)*64 + bnc) = b4[r]; }

  LOADT(0); STORET(); LOADT(1);
  asm volatile("s_waitcnt lgkmcnt(0)" ::: "memory");

  for (int it = 0; it < NT; ++it){
    const float* As = myst;
    const float* Bs = myst + 512;
#pragma unroll
    for (int kk = 0; kk < 8; ++kk){
      float4 av0 = *(const float4*)(As + kk*64 + ty*8);
      float4 av1 = *(const float4*)(As + kk*64 + ty*8 + 4);
      float4 bv0 = *(const float4*)(Bs + kk*64 + tx*8);
      float4 bv1 = *(const float4*)(Bs + kk*64 + tx*8 + 4);
      float a[8] = {av0.x,av0.y,av0.z,av0.w,av1.x,av1.y,av1.z,av1.w};
      float b[8] = {bv0.x,bv0.y,bv0.z,bv0.w,bv1.x,bv1.y,bv1.z,bv1.w};
#pragma unroll
      for (int i = 0; i < 8; i++)
#pragma unroll
        for (int j = 0; j < 8; j++) acc[i][j] = fmaf(a[i], b[j], acc[i][j]);
    }
    if (it + 1 < NT){
      asm volatile("s_waitcnt lgkmcnt(0)" ::: "memory");  // reads retired before overwrite
      STORET();                                           // (compiler inserts vmcnt for a4/b4)
      if (it + 2 < NT) LOADT(it + 2);
      asm volatile("s_waitcnt lgkmcnt(0)" ::: "memory");  // stores landed before next compute
    }
  }
#undef LOADT
#undef STORET

  // ---- log-tree cross-wave reduce: 4 -> 2 -> 1 (stride 67, proven 0-conflict R10-R18) ----
#define RWRITE(w) { float* r = lds + (w) * 4288 + lane * 67;                 \
    _Pragma("unroll")                                                        \
    for (int i = 0; i < 8; i++)                                              \
      _Pragma("unroll")                                                      \
      for (int j = 0; j < 8; j++) r[i*8 + j] = acc[i][j]; }
#define RADD(w) { const float* r = lds + (w) * 4288 + lane * 67;             \
    _Pragma("unroll")                                                        \
    for (int i = 0; i < 8; i++)                                              \
      _Pragma("unroll")                                                      \
      for (int j = 0; j < 8; j++) acc[i][j] += r[i*8 + j]; }

  __syncthreads();
  if (wv == 2 || wv == 3) RWRITE(wv - 2);
  __syncthreads();
  if (wv < 2)  RADD(wv);
  __syncthreads();
  if (wv == 1) RWRITE(0);
  __syncthreads();
  if (wv == 0){
    RADD(0);
#pragma unroll
    for (int i = 0; i < 8; i++){
      int row = mbase + ty*8 + i;
      if (row < r1){
        float* p = dst + (long long)row * N + n0 + tx*8;
        if (DENSE){
          float4 v0, v1;
          v0.x = acc[i][0]; v0.y = acc[i][1]; v0.z = acc[i][2]; v0.w = acc[i][3];
          v1.x = acc[i][4]; v1.y = acc[i][5]; v1.z = acc[i][6]; v1.w = acc[i][7];
          *(float4*)p = v0; *(float4*)(p + 4) = v1;
        } else {
#pragma unroll
          for (int j = 0; j < 8; j++)
            p[j] = fmaxf(acc[i][j] + bias[n0 + tx*8 + j], 0.0f);
        }
      }
    }
  }
#undef RWRITE
#undef RADD
}

// ---------------- per-row head: folds relu(ba+bb+ob1) / relu(bc+bd+tb1) inline (verified R17) ----
__global__ __launch_bounds__(256)
void head_kernel(const float* __restrict__ ba, const float* __restrict__ bb,
                 const float* __restrict__ bc, const float* __restrict__ bd,
                 const float* __restrict__ ob1, const float* __restrict__ tb1,
                 const float* __restrict__ ow2, const float* __restrict__ ob2,
                 const float* __restrict__ tw2, const float* __restrict__ tb2,
                 float* __restrict__ out, int* __restrict__ sel)
{
  const int b = blockIdx.x;
  const int t = threadIdx.x;
  const long long rb = (long long)b * Hdim;

  float acc[8] = {}; float accT = 0.f;
  for (int k = t; k < Hdim; k += 256){
    float hv = fmaxf(ba[rb + k] + bb[rb + k] + ob1[k], 0.f);
    float tv = fmaxf(bc[rb + k] + bd[rb + k] + tb1[k], 0.f);
    const float* w = ow2 + k * 8;
#pragma unroll
    for (int o2 = 0; o2 < 8; ++o2) acc[o2] += hv * w[o2];
    accT += tv * tw2[k];
  }
#pragma unroll
  for (int o2 = 0; o2 < 8; ++o2)
    for (int off = 32; off; off >>= 1) acc[o2] += __shfl_down(acc[o2], off);
  for (int off = 32; off; off >>= 1) accT += __shfl_down(accT, off);

  __shared__ float wred[4][9];
  __shared__ float logits[8];
  __shared__ float gum[8];
  const int wave = t >> 6, lane = t & 63;
  if (lane == 0){
#pragma unroll
    for (int o2 = 0; o2 < 8; ++o2) wred[wave][o2] = acc[o2];
    wred[wave][8] = accT;
  }
  __syncthreads();
  if (t < 9){
    float s = wred[0][t] + wred[1][t] + wred[2][t] + wred[3][t];
    if (t < 8) logits[t] = s + ob2[t];
    else       out[OFF_TERM + b] = 1.f / (1.f + expf(-(s + tb2[0])));
  }
  __syncthreads();
  if (t < 8) gum[t] = logits[t] + gumbel_at(b * 8 + t);
  __syncthreads();
  if (t == 0){
    float m = logits[0]; int am = 0;
#pragma unroll
    for (int o2 = 1; o2 < 8; ++o2) if (logits[o2] > m){ m = logits[o2]; am = o2; }
    float p[8]; float s = 0.f;
#pragma unroll
    for (int o2 = 0; o2 < 8; ++o2){ p[o2] = expf(logits[o2] - m); s += p[o2]; }
    float inv = 1.f / s;
#pragma unroll
    for (int o2 = 0; o2 < 8; ++o2) out[b * 8 + o2] = p[o2] * inv;
    out[OFF_OARG + b] = (float)am;
    float gm = gum[0]; int gs = 0;
#pragma unroll
    for (int o2 = 1; o2 < 8; ++o2) if (gum[o2] > gm){ gm = gum[o2]; gs = o2; }
    sel[b] = gs;
  }
}

// ---------------- routing: bucket samples by expert + emit row-tile list ----------------
__global__ void route_kernel(const int* __restrict__ sel, int* __restrict__ order,
                             int* __restrict__ offsets, int* __restrict__ tlist)
{
  __shared__ int cnt[8];
  __shared__ int base[8];
  const int t = threadIdx.x;
  if (t < 8) cnt[t] = 0;
  __syncthreads();
  const int s = sel[t];
  atomicAdd(&cnt[s], 1);
  __syncthreads();
  if (t == 0){
    int a = 0;
    for (int o = 0; o < 8; ++o){ offsets[o] = a; base[o] = a; a += cnt[o]; }
    offsets[8] = a;
    int nt = 0;
    for (int o = 0; o < 8; ++o)
      for (int mb = offsets[o]; mb < offsets[o] + cnt[o]; mb += 64){
        tlist[1 + 2*nt] = o; tlist[2 + 2*nt] = mb; ++nt;
      }
    tlist[0] = nt;
  }
  __syncthreads();
  const int pos = atomicAdd(&base[s], 1);
  order[pos] = t;   // permutation within an expert is nondeterministic; outputs don't depend on it
}

// ---------------- per-row output head: q = h2 @ awo + abo, softmax, argmax (R15 verbatim) ----------
__global__ __launch_bounds__(256)
void expert_out_kernel(const float* __restrict__ he2, const float* __restrict__ awo,
                       const float* __restrict__ abo,
                       const int* __restrict__ order, const int* __restrict__ offsets,
                       float* __restrict__ out)
{
  const int r = blockIdx.x;
  int o = 0;
#pragma unroll
  for (int i = 1; i < 8; ++i) if (offsets[i] <= r) o = i;
  const int t = threadIdx.x;
  const int a = t & 63, kg = t >> 6;
  const float* hrow = he2 + r * Hdim;
  const float* W = awo + o * Hdim * Aact;
  float acc = 0.f;
  const int k0 = kg * 256;
  for (int k = k0; k < k0 + 256; ++k) acc += hrow[k] * W[k * Aact + a];
  __shared__ float redm[4][64];
  redm[kg][a] = acc;
  __syncthreads();
  if (t < 64){
    float q = redm[0][a] + redm[1][a] + redm[2][a] + redm[3][a] + abo[o * Aact + a];
    float m = q;
#pragma unroll
    for (int off = 32; off; off >>= 1) m = fmaxf(m, __shfl_xor(m, off));
    float e = expf(q - m);
    float s = e;
#pragma unroll
    for (int off = 32; off; off >>= 1) s += __shfl_xor(s, off);
    const int b = order[r];
    out[OFF_ACT + b * Aact + a] = e / s;
    unsigned long long msk = __ballot(q == m);
    if (a == 0) out[OFF_SACT + b] = (float)__builtin_ctzll(msk);
  }
}

extern "C" void kernel_launch(void* const* d_in, const int* in_sizes, int n_in,
                              void* d_out, int out_size, void* d_ws, size_t ws_size,
                              hipStream_t stream)
{
  (void)in_sizes; (void)n_in; (void)out_size; (void)ws_size;
  const float* state = (const float*)d_in[0];
  const float* ow1   = (const float*)d_in[1];
  const float* ob1   = (const float*)d_in[2];
  const float* ow2   = (const float*)d_in[3];
  const float* ob2   = (const float*)d_in[4];
  const float* aw1   = (const float*)d_in[5];
  const float* ab1   = (const float*)d_in[6];
  const float* awh   = (const float*)d_in[7];
  const float* abh   = (const float*)d_in[8];
  const float* awo   = (const float*)d_in[9];
  const float* abo   = (const float*)d_in[10];
  const float* tw1   = (const float*)d_in[11];
  const float* tb1   = (const float*)d_in[12];
  const float* tw2   = (const float*)d_in[13];
  const float* tb2   = (const float*)d_in[14];
  float* out = (float*)d_out;

  // dense split-K pairs: opt={ba,bb}, term={bc,bd} (head folds). ba reused as L1 out (relu'd),
  // bc reused as L2 out (relu'd) afterwards.
  float* ba = (float*)d_ws;
  float* bb = ba + (long long)Bsz * Hdim;
  float* bc = bb + (long long)Bsz * Hdim;
  float* bd = bc + (long long)Bsz * Hdim;
  int* sel     = (int*)(bd + (long long)Bsz * Hdim);
  int* order   = sel + Bsz;
  int* offsets = order + Bsz;
  int* tlist   = offsets + 9;           // [ntiles | (expert,mbase) * MAXT]

  // 1. dense pair raw sums, global split-K x2: opt kb0->ba kb1->bb; term kb0->bc kb1->bd
  gemm_splitk<false,true><<<dim3(16,16,4), 256, 0, stream>>>(
      state, Din, ow1, tw1, 0, nullptr, nullptr, 0, ba, bc, bb, bd,
      Hdim, Din, nullptr, nullptr, nullptr);
  // 2. heads (fold dense sums+bias+relu): opt softmax/argmax, gumbel sel, termination
  head_kernel<<<dim3(Bsz), 256, 0, stream>>>(
      ba, bb, bc, bd, ob1, tb1, ow2, ob2, tw2, tb2, out, sel);
  // 3. bucket samples by expert + tile list
  route_kernel<<<dim3(1), 1024, 0, stream>>>(sel, order, offsets, tlist);
  // 4. expert L1 (gather state rows, bias+relu epilogue): ba[r] = relu(state[order[r]] @ aw1[o] + ab1[o])
  gemm_splitk<true,false><<<dim3(MAXT,16), 256, 0, stream>>>(
      state, Din, aw1, nullptr, (long long)Din*Hdim, ab1, nullptr, Hdim,
      ba, nullptr, nullptr, nullptr, Hdim, Din, order, offsets, tlist);
  // 5. expert L2 (bias+relu epilogue): bc[r] = relu(ba[r] @ awh[o,0] + abh[o,0])
  gemm_splitk<false,false><<<dim3(MAXT,16), 256, 0, stream>>>(
      ba, Hdim, awh, nullptr, (long long)Hdim*Hdim, abh, nullptr, Hdim,
      bc, nullptr, nullptr, nullptr, Hdim, Hdim, nullptr, offsets, tlist);
  // 6. output head: q, action softmax, selected action
  expert_out_kernel<<<dim3(Bsz), 256, 0, stream>>>(bc, awo, abo, order, offsets, out);
}

// Round 20
// 125.492 us; speedup vs baseline: 1.4571x; 1.2679x over previous
//
#include <hip/hip_runtime.h>
#include <math.h>

#define Bsz 1024
#define Din 512
#define Hdim 1024
#define Aact 64
#define MAXT 23   // max row-tiles across experts: 7 partial + 16

// out layout (float32): option_probs[1024*8] | action_probs[1024*64] | term[1024] | opt_argmax[1024] | sel_action[1024]
#define OFF_ACT   8192
#define OFF_TERM  73728
#define OFF_OARG  74752
#define OFF_SACT  75776

typedef __attribute__((ext_vector_type(8))) short bf16x8;
typedef __attribute__((ext_vector_type(4))) float f32x4;

// ---------------- threefry2x32-20, key (0,42), partitionable XOR-fold (verified R3-R19) ----------------
__device__ __forceinline__ unsigned rotl32(unsigned x, int d){ return (x << d) | (x >> (32 - d)); }

__device__ __forceinline__ void threefry_042(unsigned& x0, unsigned& x1){
  const unsigned ks0 = 0u, ks1 = 42u, ks2 = 0x1BD11BDAu ^ 0u ^ 42u;
  x0 += ks0; x1 += ks1;
#define TFR(r) { x0 += x1; x1 = rotl32(x1, r); x1 ^= x0; }
  TFR(13) TFR(15) TFR(26) TFR(6)  x0 += ks1; x1 += ks2 + 1u;
  TFR(17) TFR(29) TFR(16) TFR(24) x0 += ks2; x1 += ks0 + 2u;
  TFR(13) TFR(15) TFR(26) TFR(6)  x0 += ks0; x1 += ks1 + 3u;
  TFR(17) TFR(29) TFR(16) TFR(24) x0 += ks1; x1 += ks2 + 4u;
  TFR(13) TFR(15) TFR(26) TFR(6)  x0 += ks2; x1 += ks0 + 5u;
#undef TFR
}

__device__ __forceinline__ float gumbel_at(int idx){
  unsigned x0 = 0u, x1 = (unsigned)idx;
  threefry_042(x0, x1);
  unsigned bits = x0 ^ x1;
  float f = __uint_as_float((bits >> 9) | 0x3F800000u) - 1.0f;
  float u = fmaxf(f, 1.1754944e-38f);
  return -logf(-logf(u));
}

// ---------------- bf16 hi/lo split helpers (RNE) ----------------
__device__ __forceinline__ unsigned short bf16_rne(float x){
  unsigned u = __float_as_uint(x);
  return (unsigned short)((u + 0x7FFFu + ((u >> 16) & 1u)) >> 16);
}
__device__ __forceinline__ float bf16_tof(unsigned short h){
  return __uint_as_float(((unsigned)h) << 16);
}

// ---------------- state -> hi/lo bf16 (row-major, same indexing) ----------------
__global__ __launch_bounds__(256)
void convert_state(const float* __restrict__ st, unsigned short* __restrict__ hi,
                   unsigned short* __restrict__ lo)
{
  const int i = (blockIdx.x * 256 + threadIdx.x) * 4;   // 512 blocks x 256 x 4 = 524288
  float4 v = *(const float4*)(st + i);
  ushort4 h, l;
  h.x = bf16_rne(v.x); l.x = bf16_rne(v.x - bf16_tof(h.x));
  h.y = bf16_rne(v.y); l.y = bf16_rne(v.y - bf16_tof(h.y));
  h.z = bf16_rne(v.z); l.z = bf16_rne(v.z - bf16_tof(h.z));
  h.w = bf16_rne(v.w); l.w = bf16_rne(v.w - bf16_tof(h.w));
  *(ushort4*)(hi + i) = h;
  *(ushort4*)(lo + i) = l;
}

// ---------------- bf16x3 MFMA GEMM: 64x64 tile, 4 waves = 32x32 quadrants ----------------
// C = relu(A @ W + bias), A pre-split hi/lo bf16 row-major [M][K]; W fp32 [K][N] (split in staging).
// a*b ~= ahi*bhi + ahi*blo + alo*bhi (fp32 MFMA accum); error ~2^-18 rel == fp32-reorder class.
// LDS fragment order [kb4][row/col 64][e8]; A-stage = b128 copies; B-stage = scalar load + 2 b16.
// mfma_f32_16x16x32_bf16 layouts: A row=l&15,k=(l>>4)*8+e; B col=l&15; D col=l&15,row=(l>>4)*4+r.
// HILOOUT: epilogue emits hi/lo bf16 (feeds next GEMM's A); else fp32.
template<bool DENSE, bool GATHER, bool HILOOUT>
__global__ __launch_bounds__(256)
void mfma_gemm(const unsigned short* __restrict__ Ahi, const unsigned short* __restrict__ Alo,
               int lda,
               const float* __restrict__ W0, const float* __restrict__ W1, long long wstride,
               const float* __restrict__ b0, const float* __restrict__ b1, int bstride,
               float* __restrict__ C0, float* __restrict__ C1,
               unsigned short* __restrict__ Chi, unsigned short* __restrict__ Clo,
               int N, int K,
               const int* __restrict__ order, const int* __restrict__ offsets,
               const int* __restrict__ tlist)
{
  const float* W; const float* bias; float* C;
  int mbase, r1, n0;
  if (DENSE){
    const int z = blockIdx.z;
    mbase = blockIdx.x * 64; r1 = Bsz; n0 = blockIdx.y * 64;
    W = z ? W1 : W0; bias = z ? b1 : b0; C = z ? C1 : C0;
  } else {
    const int i = blockIdx.x;
    if (i >= tlist[0]) return;
    const int o = tlist[1 + 2*i];
    mbase = tlist[2 + 2*i];
    r1 = offsets[o + 1];
    n0 = blockIdx.y * 64;
    W = W0 + (long long)o * wstride; bias = b0 + o * bstride; C = C0;
  }

  __shared__ unsigned short sAh[2048], sAl[2048], sBh[2048], sBl[2048];   // 16KB

  const int tid = threadIdx.x;
  const int wv = tid >> 6, lane = tid & 63;

  // A staging role: thread -> (row = tid&63, k-block = tid>>6)
  const int ar = tid & 63, akb = tid >> 6;
  int grow = mbase + ar;
  int arow = grow < r1 ? grow : mbase;
  if (GATHER) arow = order[arow];
  const unsigned short* pAh = Ahi + (long long)arow * lda;
  const unsigned short* pAl = Alo + (long long)arow * lda;

  const int qr = (wv >> 1) * 32, qc = (wv & 1) * 32;   // wave quadrant

  f32x4 acc[2][2];
#pragma unroll
  for (int a = 0; a < 2; a++)
#pragma unroll
    for (int b = 0; b < 2; b++) acc[a][b] = (f32x4){0.f, 0.f, 0.f, 0.f};

  for (int kt = 0; kt < K; kt += 32){
    // ---- stage A: fragment-order b128 copies (conflict-free) ----
    {
      const int off = kt + akb * 8;
      *(float4*)(sAh + akb*512 + ar*8) = *(const float4*)(pAh + off);
      *(float4*)(sAl + akb*512 + ar*8) = *(const float4*)(pAl + off);
    }
    // ---- stage B: wave wv covers k-rows wv*8..wv*8+7, all 64 lanes = cols (coalesced loads) ----
#pragma unroll
    for (int rr = 0; rr < 8; rr++){
      const int kl = wv * 8 + rr;
      const float v = W[(long long)(kt + kl) * N + n0 + lane];
      const unsigned short h = bf16_rne(v);
      sBh[wv*512 + lane*8 + rr] = h;
      sBl[wv*512 + lane*8 + rr] = bf16_rne(v - bf16_tof(h));
    }
    __syncthreads();
    // ---- compute: 8 frag reads + 12 mfma ----
    {
      const int g = (lane >> 4) * 512, li = lane & 15;
      bf16x8 a0h = *(const bf16x8*)(sAh + g + (qr + li) * 8);
      bf16x8 a1h = *(const bf16x8*)(sAh + g + (qr + 16 + li) * 8);
      bf16x8 a0l = *(const bf16x8*)(sAl + g + (qr + li) * 8);
      bf16x8 a1l = *(const bf16x8*)(sAl + g + (qr + 16 + li) * 8);
      bf16x8 b0h = *(const bf16x8*)(sBh + g + (qc + li) * 8);
      bf16x8 b1h = *(const bf16x8*)(sBh + g + (qc + 16 + li) * 8);
      bf16x8 b0l = *(const bf16x8*)(sBl + g + (qc + li) * 8);
      bf16x8 b1l = *(const bf16x8*)(sBl + g + (qc + 16 + li) * 8);
      acc[0][0] = __builtin_amdgcn_mfma_f32_16x16x32_bf16(a0h, b0h, acc[0][0], 0, 0, 0);
      acc[0][1] = __builtin_amdgcn_mfma_f32_16x16x32_bf16(a0h, b1h, acc[0][1], 0, 0, 0);
      acc[1][0] = __builtin_amdgcn_mfma_f32_16x16x32_bf16(a1h, b0h, acc[1][0], 0, 0, 0);
      acc[1][1] = __builtin_amdgcn_mfma_f32_16x16x32_bf16(a1h, b1h, acc[1][1], 0, 0, 0);
      acc[0][0] = __builtin_amdgcn_mfma_f32_16x16x32_bf16(a0h, b0l, acc[0][0], 0, 0, 0);
      acc[0][1] = __builtin_amdgcn_mfma_f32_16x16x32_bf16(a0h, b1l, acc[0][1], 0, 0, 0);
      acc[1][0] = __builtin_amdgcn_mfma_f32_16x16x32_bf16(a1h, b0l, acc[1][0], 0, 0, 0);
      acc[1][1] = __builtin_amdgcn_mfma_f32_16x16x32_bf16(a1h, b1l, acc[1][1], 0, 0, 0);
      acc[0][0] = __builtin_amdgcn_mfma_f32_16x16x32_bf16(a0l, b0h, acc[0][0], 0, 0, 0);
      acc[0][1] = __builtin_amdgcn_mfma_f32_16x16x32_bf16(a0l, b1h, acc[0][1], 0, 0, 0);
      acc[1][0] = __builtin_amdgcn_mfma_f32_16x16x32_bf16(a1l, b0h, acc[1][0], 0, 0, 0);
      acc[1][1] = __builtin_amdgcn_mfma_f32_16x16x32_bf16(a1l, b1h, acc[1][1], 0, 0, 0);
    }
    __syncthreads();
  }

  // ---- epilogue: D col=lane&15, row=(lane>>4)*4+r ----
#pragma unroll
  for (int rb = 0; rb < 2; rb++)
#pragma unroll
    for (int cb = 0; cb < 2; cb++){
      const int col = n0 + qc + cb*16 + (lane & 15);
      const float bv = bias[col];
#pragma unroll
      for (int r = 0; r < 4; r++){
        const int row = mbase + qr + rb*16 + (lane >> 4)*4 + r;
        if (row < r1){
          const float v = fmaxf(acc[rb][cb][r] + bv, 0.f);
          if (HILOOUT){
            const unsigned short h = bf16_rne(v);
            Chi[(long long)row * N + col] = h;
            Clo[(long long)row * N + col] = bf16_rne(v - bf16_tof(h));
          } else {
            C[(long long)row * N + col] = v;
          }
        }
      }
    }
}

// ---------------- per-row head: opt logits + softmax + argmax + gumbel sel + termination ----------------
__global__ __launch_bounds__(256)
void head_kernel(const float* __restrict__ h1, const float* __restrict__ th,
                 const float* __restrict__ ow2, const float* __restrict__ ob2,
                 const float* __restrict__ tw2, const float* __restrict__ tb2,
                 float* __restrict__ out, int* __restrict__ sel)
{
  const int b = blockIdx.x;
  const int t = threadIdx.x;
  const float* hrow = h1 + b * Hdim;
  const float* trow = th + b * Hdim;

  float acc[8] = {}; float accT = 0.f;
  for (int k = t; k < Hdim; k += 256){
    float hv = hrow[k];
    const float* w = ow2 + k * 8;
#pragma unroll
    for (int o2 = 0; o2 < 8; ++o2) acc[o2] += hv * w[o2];
    accT += trow[k] * tw2[k];
  }
#pragma unroll
  for (int o2 = 0; o2 < 8; ++o2)
    for (int off = 32; off; off >>= 1) acc[o2] += __shfl_down(acc[o2], off);
  for (int off = 32; off; off >>= 1) accT += __shfl_down(accT, off);

  __shared__ float wred[4][9];
  __shared__ float logits[8];
  __shared__ float gum[8];
  const int wave = t >> 6, lane = t & 63;
  if (lane == 0){
#pragma unroll
    for (int o2 = 0; o2 < 8; ++o2) wred[wave][o2] = acc[o2];
    wred[wave][8] = accT;
  }
  __syncthreads();
  if (t < 9){
    float s = wred[0][t] + wred[1][t] + wred[2][t] + wred[3][t];
    if (t < 8) logits[t] = s + ob2[t];
    else       out[OFF_TERM + b] = 1.f / (1.f + expf(-(s + tb2[0])));
  }
  __syncthreads();
  if (t < 8) gum[t] = logits[t] + gumbel_at(b * 8 + t);
  __syncthreads();
  if (t == 0){
    float m = logits[0]; int am = 0;
#pragma unroll
    for (int o2 = 1; o2 < 8; ++o2) if (logits[o2] > m){ m = logits[o2]; am = o2; }
    float p[8]; float s = 0.f;
#pragma unroll
    for (int o2 = 0; o2 < 8; ++o2){ p[o2] = expf(logits[o2] - m); s += p[o2]; }
    float inv = 1.f / s;
#pragma unroll
    for (int o2 = 0; o2 < 8; ++o2) out[b * 8 + o2] = p[o2] * inv;
    out[OFF_OARG + b] = (float)am;
    float gm = gum[0]; int gs = 0;
#pragma unroll
    for (int o2 = 1; o2 < 8; ++o2) if (gum[o2] > gm){ gm = gum[o2]; gs = o2; }
    sel[b] = gs;
  }
}

// ---------------- routing: bucket samples by expert + emit row-tile list ----------------
__global__ void route_kernel(const int* __restrict__ sel, int* __restrict__ order,
                             int* __restrict__ offsets, int* __restrict__ tlist)
{
  __shared__ int cnt[8];
  __shared__ int base[8];
  const int t = threadIdx.x;
  if (t < 8) cnt[t] = 0;
  __syncthreads();
  const int s = sel[t];
  atomicAdd(&cnt[s], 1);
  __syncthreads();
  if (t == 0){
    int a = 0;
    for (int o = 0; o < 8; ++o){ offsets[o] = a; base[o] = a; a += cnt[o]; }
    offsets[8] = a;
    int nt = 0;
    for (int o = 0; o < 8; ++o)
      for (int mb = offsets[o]; mb < offsets[o] + cnt[o]; mb += 64){
        tlist[1 + 2*nt] = o; tlist[2 + 2*nt] = mb; ++nt;
      }
    tlist[0] = nt;
  }
  __syncthreads();
  const int pos = atomicAdd(&base[s], 1);
  order[pos] = t;   // permutation within an expert is nondeterministic; outputs don't depend on it
}

// ---------------- per-row output head: q = h2 @ awo + abo, softmax, argmax ----------------
__global__ __launch_bounds__(256)
void expert_out_kernel(const float* __restrict__ he2, const float* __restrict__ awo,
                       const float* __restrict__ abo,
                       const int* __restrict__ order, const int* __restrict__ offsets,
                       float* __restrict__ out)
{
  const int r = blockIdx.x;
  int o = 0;
#pragma unroll
  for (int i = 1; i < 8; ++i) if (offsets[i] <= r) o = i;
  const int t = threadIdx.x;
  const int a = t & 63, kg = t >> 6;
  const float* hrow = he2 + r * Hdim;
  const float* W = awo + o * Hdim * Aact;
  float acc = 0.f;
  const int k0 = kg * 256;
  for (int k = k0; k < k0 + 256; ++k) acc += hrow[k] * W[k * Aact + a];
  __shared__ float redm[4][64];
  redm[kg][a] = acc;
  __syncthreads();
  if (t < 64){
    float q = redm[0][a] + redm[1][a] + redm[2][a] + redm[3][a] + abo[o * Aact + a];
    float m = q;
#pragma unroll
    for (int off = 32; off; off >>= 1) m = fmaxf(m, __shfl_xor(m, off));
    float e = expf(q - m);
    float s = e;
#pragma unroll
    for (int off = 32; off; off >>= 1) s += __shfl_xor(s, off);
    const int b = order[r];
    out[OFF_ACT + b * Aact + a] = e / s;
    unsigned long long msk = __ballot(q == m);
    if (a == 0) out[OFF_SACT + b] = (float)__builtin_ctzll(msk);
  }
}

extern "C" void kernel_launch(void* const* d_in, const int* in_sizes, int n_in,
                              void* d_out, int out_size, void* d_ws, size_t ws_size,
                              hipStream_t stream)
{
  (void)in_sizes; (void)n_in; (void)out_size; (void)ws_size;
  const float* state = (const float*)d_in[0];
  const float* ow1   = (const float*)d_in[1];
  const float* ob1   = (const float*)d_in[2];
  const float* ow2   = (const float*)d_in[3];
  const float* ob2   = (const float*)d_in[4];
  const float* aw1   = (const float*)d_in[5];
  const float* ab1   = (const float*)d_in[6];
  const float* awh   = (const float*)d_in[7];
  const float* abh   = (const float*)d_in[8];
  const float* awo   = (const float*)d_in[9];
  const float* abo   = (const float*)d_in[10];
  const float* tw1   = (const float*)d_in[11];
  const float* tb1   = (const float*)d_in[12];
  const float* tw2   = (const float*)d_in[13];
  const float* tb2   = (const float*)d_in[14];
  float* out = (float*)d_out;

  float* h1 = (float*)d_ws;                                 // dense opt hidden (fp32)
  float* h2 = h1 + (long long)Bsz * Hdim;                   // dense term hidden -> L2 out (fp32)
  unsigned short* sthi = (unsigned short*)(h2 + (long long)Bsz * Hdim);  // state hi [1024][512]
  unsigned short* stlo = sthi + (long long)Bsz * Din;
  unsigned short* h1hi = stlo + (long long)Bsz * Din;       // L1 out hi [1024][1024]
  unsigned short* h1lo = h1hi + (long long)Bsz * Hdim;
  int* sel     = (int*)(h1lo + (long long)Bsz * Hdim);
  int* order   = sel + Bsz;
  int* offsets = order + Bsz;
  int* tlist   = offsets + 9;           // [ntiles | (expert,mbase) * MAXT]

  // 1. state -> hi/lo bf16
  convert_state<<<dim3(512), 256, 0, stream>>>(state, sthi, stlo);
  // 2. dense pair: h1 = relu(st @ ow1 + ob1), h2 = relu(st @ tw1 + tb1)   [bf16x3 MFMA]
  mfma_gemm<true, false, false><<<dim3(16, 16, 2), 256, 0, stream>>>(
      sthi, stlo, Din, ow1, tw1, 0, ob1, tb1, 0, h1, h2, nullptr, nullptr,
      Hdim, Din, nullptr, nullptr, nullptr);
  // 3. heads: opt softmax/argmax, gumbel categorical sel, termination sigmoid
  head_kernel<<<dim3(Bsz), 256, 0, stream>>>(h1, h2, ow2, ob2, tw2, tb2, out, sel);
  // 4. bucket samples by expert + tile list
  route_kernel<<<dim3(1), 1024, 0, stream>>>(sel, order, offsets, tlist);
  // 5. expert L1 (gather state rows): h1hi/lo[r] = split(relu(state[order[r]] @ aw1[o] + ab1[o]))
  mfma_gemm<false, true, true><<<dim3(MAXT, 16), 256, 0, stream>>>(
      sthi, stlo, Din, aw1, nullptr, (long long)Din*Hdim, ab1, nullptr, Hdim,
      nullptr, nullptr, h1hi, h1lo, Hdim, Din, order, offsets, tlist);
  // 6. expert L2: h2[r] = relu(h1[r] @ awh[o,0] + abh[o,0])   [A already hi/lo]
  mfma_gemm<false, false, false><<<dim3(MAXT, 16), 256, 0, stream>>>(
      h1hi, h1lo, Hdim, awh, nullptr, (long long)Hdim*Hdim, abh, nullptr, Hdim,
      h2, nullptr, nullptr, nullptr, Hdim, Hdim, nullptr, offsets, tlist);
  // 7. output head: q, action softmax, selected action
  expert_out_kernel<<<dim3(Bsz), 256, 0, stream>>>(h2, awo, abo, order, offsets, out);
}

// Round 21
// 110.357 us; speedup vs baseline: 1.6569x; 1.1371x over previous
//
#include <hip/hip_runtime.h>
#include <math.h>

#define Bsz 1024
#define Din 512
#define Hdim 1024
#define Aact 64
#define MAXT 23   // max row-tiles across experts: 7 partial + 16
#define NXCD 8

// out layout (float32): option_probs[1024*8] | action_probs[1024*64] | term[1024] | opt_argmax[1024] | sel_action[1024]
#define OFF_ACT   8192
#define OFF_TERM  73728
#define OFF_OARG  74752
#define OFF_SACT  75776

typedef __attribute__((ext_vector_type(8))) short bf16x8;
typedef __attribute__((ext_vector_type(4))) float f32x4;

// ---------------- threefry2x32-20, key (0,42), partitionable XOR-fold (verified R3-R20) ----------------
__device__ __forceinline__ unsigned rotl32(unsigned x, int d){ return (x << d) | (x >> (32 - d)); }

__device__ __forceinline__ void threefry_042(unsigned& x0, unsigned& x1){
  const unsigned ks0 = 0u, ks1 = 42u, ks2 = 0x1BD11BDAu ^ 0u ^ 42u;
  x0 += ks0; x1 += ks1;
#define TFR(r) { x0 += x1; x1 = rotl32(x1, r); x1 ^= x0; }
  TFR(13) TFR(15) TFR(26) TFR(6)  x0 += ks1; x1 += ks2 + 1u;
  TFR(17) TFR(29) TFR(16) TFR(24) x0 += ks2; x1 += ks0 + 2u;
  TFR(13) TFR(15) TFR(26) TFR(6)  x0 += ks0; x1 += ks1 + 3u;
  TFR(17) TFR(29) TFR(16) TFR(24) x0 += ks1; x1 += ks2 + 4u;
  TFR(13) TFR(15) TFR(26) TFR(6)  x0 += ks2; x1 += ks0 + 5u;
#undef TFR
}

__device__ __forceinline__ float gumbel_at(int idx){
  unsigned x0 = 0u, x1 = (unsigned)idx;
  threefry_042(x0, x1);
  unsigned bits = x0 ^ x1;
  float f = __uint_as_float((bits >> 9) | 0x3F800000u) - 1.0f;
  float u = fmaxf(f, 1.1754944e-38f);
  return -logf(-logf(u));
}

// ---------------- bf16 hi/lo split helpers (RNE) ----------------
__device__ __forceinline__ unsigned short bf16_rne(float x){
  unsigned u = __float_as_uint(x);
  return (unsigned short)((u + 0x7FFFu + ((u >> 16) & 1u)) >> 16);
}
__device__ __forceinline__ float bf16_tof(unsigned short h){
  return __uint_as_float(((unsigned)h) << 16);
}

// ---------------- state -> hi/lo bf16 (row-major, same indexing) ----------------
__global__ __launch_bounds__(256)
void convert_state(const float* __restrict__ st, unsigned short* __restrict__ hi,
                   unsigned short* __restrict__ lo)
{
  const int i = (blockIdx.x * 256 + threadIdx.x) * 4;   // 512 blocks x 256 x 4 = 524288
  float4 v = *(const float4*)(st + i);
  ushort4 h, l;
  h.x = bf16_rne(v.x); l.x = bf16_rne(v.x - bf16_tof(h.x));
  h.y = bf16_rne(v.y); l.y = bf16_rne(v.y - bf16_tof(h.y));
  h.z = bf16_rne(v.z); l.z = bf16_rne(v.z - bf16_tof(h.z));
  h.w = bf16_rne(v.w); l.w = bf16_rne(v.w - bf16_tof(h.w));
  *(ushort4*)(hi + i) = h;
  *(ushort4*)(lo + i) = l;
}

// ---------------- bf16x3 MFMA GEMM: 64x64 tile, 4 waves = 32x32 quadrants, k-step 64 ----------------
// R21 = R20's verified kernel + (1) T1 bijective XCD swizzle on both grids (R20 dropped it:
// FETCH 57MB vs 6MB unique = 8x cross-XCD re-fetch, fetch-bound at ~1.2TB/s) and
// (2) k-step 32->64 (halve barrier rounds; 24 MFMA/wave/phase; LDS 32KB).
// a*b ~= ahi*bhi + ahi*blo + alo*bhi (fp32 MFMA accum); error class == fp32 split-K reorder.
// mfma_f32_16x16x32_bf16 layouts: A row=l&15,k=(l>>4)*8+e; B col=l&15; D col=l&15,row=(l>>4)*4+r.
template<bool DENSE, bool GATHER, bool HILOOUT>
__global__ __launch_bounds__(256)
void mfma_gemm(const unsigned short* __restrict__ Ahi, const unsigned short* __restrict__ Alo,
               int lda,
               const float* __restrict__ W0, const float* __restrict__ W1, long long wstride,
               const float* __restrict__ b0, const float* __restrict__ b1, int bstride,
               float* __restrict__ C0, float* __restrict__ C1,
               unsigned short* __restrict__ Chi, unsigned short* __restrict__ Clo,
               int N, int K,
               const int* __restrict__ order, const int* __restrict__ offsets,
               const int* __restrict__ tlist)
{
  const float* W; const float* bias; float* C;
  int mbase, r1, n0;
  if (DENSE){
    // 512 blocks; bijective XCD swizzle: chunk of 64 = {1 net, 4 m-tiles, all 16 n} ~2.5MB < L2
    const int bid = (int)(blockIdx.x + 16u*blockIdx.y + 256u*blockIdx.z);
    const int wf = (bid & 7) * 64 + (bid >> 3);
    const int ny = wf & 15, mx = (wf >> 4) & 15, z = wf >> 8;
    mbase = mx * 64; r1 = Bsz; n0 = ny * 64;
    W = z ? W1 : W0; bias = z ? b1 : b0; C = z ? C1 : C0;
  } else {
    // 368 = 46*8 blocks, R11-verified grouped swizzle (n fastest within chunk)
    const int bid = (int)(blockIdx.x + gridDim.x * blockIdx.y);
    const int wf = (bid % NXCD) * ((MAXT * 16) / NXCD) + bid / NXCD;
    const int i = wf >> 4;
    if (i >= tlist[0]) return;
    const int o = tlist[1 + 2*i];
    mbase = tlist[2 + 2*i];
    r1 = offsets[o + 1];
    n0 = (wf & 15) * 64;
    W = W0 + (long long)o * wstride; bias = b0 + o * bstride; C = C0;
  }

  __shared__ unsigned short sAh[4096], sAl[4096], sBh[4096], sBl[4096];   // 32KB, k-step 64

  const int tid = threadIdx.x;
  const int wv = tid >> 6, lane = tid & 63;

  // A staging role: thread -> (row = tid&63, k-block pair = tid>>6 and +4)
  const int ar = tid & 63, akb = tid >> 6;
  int grow = mbase + ar;
  int arow = grow < r1 ? grow : mbase;
  if (GATHER) arow = order[arow];
  const unsigned short* pAh = Ahi + (long long)arow * lda;
  const unsigned short* pAl = Alo + (long long)arow * lda;

  const int qr = (wv >> 1) * 32, qc = (wv & 1) * 32;   // wave quadrant

  f32x4 acc[2][2];
#pragma unroll
  for (int a = 0; a < 2; a++)
#pragma unroll
    for (int b = 0; b < 2; b++) acc[a][b] = (f32x4){0.f, 0.f, 0.f, 0.f};

  for (int kt = 0; kt < K; kt += 64){
    // ---- stage A: fragment-order b128 copies, kb akb and akb+4 ----
#pragma unroll
    for (int h = 0; h < 2; h++){
      const int kb = akb + h*4;
      *(float4*)(sAh + kb*512 + ar*8) = *(const float4*)(pAh + kt + kb*8);
      *(float4*)(sAl + kb*512 + ar*8) = *(const float4*)(pAl + kt + kb*8);
    }
    // ---- stage B: wave wv covers k-rows wv*16..+15, 64 lanes = cols (coalesced) ----
#pragma unroll
    for (int rr = 0; rr < 16; rr++){
      const int kl = wv * 16 + rr;
      const int kb = kl >> 3, e = kl & 7;
      const float v = W[(long long)(kt + kl) * N + n0 + lane];
      const unsigned short h = bf16_rne(v);
      sBh[kb*512 + lane*8 + e] = h;
      sBl[kb*512 + lane*8 + e] = bf16_rne(v - bf16_tof(h));
    }
    __syncthreads();
    // ---- compute: 2 k32 groups x (8 frag reads + 12 mfma) ----
#pragma unroll
    for (int kg = 0; kg < 2; kg++){
      const int g = (kg*4 + (lane >> 4)) * 512, li = lane & 15;
      bf16x8 a0h = *(const bf16x8*)(sAh + g + (qr + li) * 8);
      bf16x8 a1h = *(const bf16x8*)(sAh + g + (qr + 16 + li) * 8);
      bf16x8 a0l = *(const bf16x8*)(sAl + g + (qr + li) * 8);
      bf16x8 a1l = *(const bf16x8*)(sAl + g + (qr + 16 + li) * 8);
      bf16x8 b0h = *(const bf16x8*)(sBh + g + (qc + li) * 8);
      bf16x8 b1h = *(const bf16x8*)(sBh + g + (qc + 16 + li) * 8);
      bf16x8 b0l = *(const bf16x8*)(sBl + g + (qc + li) * 8);
      bf16x8 b1l = *(const bf16x8*)(sBl + g + (qc + 16 + li) * 8);
      acc[0][0] = __builtin_amdgcn_mfma_f32_16x16x32_bf16(a0h, b0h, acc[0][0], 0, 0, 0);
      acc[0][1] = __builtin_amdgcn_mfma_f32_16x16x32_bf16(a0h, b1h, acc[0][1], 0, 0, 0);
      acc[1][0] = __builtin_amdgcn_mfma_f32_16x16x32_bf16(a1h, b0h, acc[1][0], 0, 0, 0);
      acc[1][1] = __builtin_amdgcn_mfma_f32_16x16x32_bf16(a1h, b1h, acc[1][1], 0, 0, 0);
      acc[0][0] = __builtin_amdgcn_mfma_f32_16x16x32_bf16(a0h, b0l, acc[0][0], 0, 0, 0);
      acc[0][1] = __builtin_amdgcn_mfma_f32_16x16x32_bf16(a0h, b1l, acc[0][1], 0, 0, 0);
      acc[1][0] = __builtin_amdgcn_mfma_f32_16x16x32_bf16(a1h, b0l, acc[1][0], 0, 0, 0);
      acc[1][1] = __builtin_amdgcn_mfma_f32_16x16x32_bf16(a1h, b1l, acc[1][1], 0, 0, 0);
      acc[0][0] = __builtin_amdgcn_mfma_f32_16x16x32_bf16(a0l, b0h, acc[0][0], 0, 0, 0);
      acc[0][1] = __builtin_amdgcn_mfma_f32_16x16x32_bf16(a0l, b1h, acc[0][1], 0, 0, 0);
      acc[1][0] = __builtin_amdgcn_mfma_f32_16x16x32_bf16(a1l, b0h, acc[1][0], 0, 0, 0);
      acc[1][1] = __builtin_amdgcn_mfma_f32_16x16x32_bf16(a1l, b1h, acc[1][1], 0, 0, 0);
    }
    __syncthreads();
  }

  // ---- epilogue: D col=lane&15, row=(lane>>4)*4+r ----
#pragma unroll
  for (int rb = 0; rb < 2; rb++)
#pragma unroll
    for (int cb = 0; cb < 2; cb++){
      const int col = n0 + qc + cb*16 + (lane & 15);
      const float bv = bias[col];
#pragma unroll
      for (int r = 0; r < 4; r++){
        const int row = mbase + qr + rb*16 + (lane >> 4)*4 + r;
        if (row < r1){
          const float v = fmaxf(acc[rb][cb][r] + bv, 0.f);
          if (HILOOUT){
            const unsigned short h = bf16_rne(v);
            Chi[(long long)row * N + col] = h;
            Clo[(long long)row * N + col] = bf16_rne(v - bf16_tof(h));
          } else {
            C[(long long)row * N + col] = v;
          }
        }
      }
    }
}

// ---------------- per-row head: opt logits + softmax + argmax + gumbel sel + termination ----------------
__global__ __launch_bounds__(256)
void head_kernel(const float* __restrict__ h1, const float* __restrict__ th,
                 const float* __restrict__ ow2, const float* __restrict__ ob2,
                 const float* __restrict__ tw2, const float* __restrict__ tb2,
                 float* __restrict__ out, int* __restrict__ sel)
{
  const int b = blockIdx.x;
  const int t = threadIdx.x;
  const float* hrow = h1 + b * Hdim;
  const float* trow = th + b * Hdim;

  float acc[8] = {}; float accT = 0.f;
  for (int k = t; k < Hdim; k += 256){
    float hv = hrow[k];
    const float* w = ow2 + k * 8;
#pragma unroll
    for (int o2 = 0; o2 < 8; ++o2) acc[o2] += hv * w[o2];
    accT += trow[k] * tw2[k];
  }
#pragma unroll
  for (int o2 = 0; o2 < 8; ++o2)
    for (int off = 32; off; off >>= 1) acc[o2] += __shfl_down(acc[o2], off);
  for (int off = 32; off; off >>= 1) accT += __shfl_down(accT, off);

  __shared__ float wred[4][9];
  __shared__ float logits[8];
  __shared__ float gum[8];
  const int wave = t >> 6, lane = t & 63;
  if (lane == 0){
#pragma unroll
    for (int o2 = 0; o2 < 8; ++o2) wred[wave][o2] = acc[o2];
    wred[wave][8] = accT;
  }
  __syncthreads();
  if (t < 9){
    float s = wred[0][t] + wred[1][t] + wred[2][t] + wred[3][t];
    if (t < 8) logits[t] = s + ob2[t];
    else       out[OFF_TERM + b] = 1.f / (1.f + expf(-(s + tb2[0])));
  }
  __syncthreads();
  if (t < 8) gum[t] = logits[t] + gumbel_at(b * 8 + t);
  __syncthreads();
  if (t == 0){
    float m = logits[0]; int am = 0;
#pragma unroll
    for (int o2 = 1; o2 < 8; ++o2) if (logits[o2] > m){ m = logits[o2]; am = o2; }
    float p[8]; float s = 0.f;
#pragma unroll
    for (int o2 = 0; o2 < 8; ++o2){ p[o2] = expf(logits[o2] - m); s += p[o2]; }
    float inv = 1.f / s;
#pragma unroll
    for (int o2 = 0; o2 < 8; ++o2) out[b * 8 + o2] = p[o2] * inv;
    out[OFF_OARG + b] = (float)am;
    float gm = gum[0]; int gs = 0;
#pragma unroll
    for (int o2 = 1; o2 < 8; ++o2) if (gum[o2] > gm){ gm = gum[o2]; gs = o2; }
    sel[b] = gs;
  }
}

// ---------------- routing: bucket samples by expert + emit row-tile list ----------------
__global__ void route_kernel(const int* __restrict__ sel, int* __restrict__ order,
                             int* __restrict__ offsets, int* __restrict__ tlist)
{
  __shared__ int cnt[8];
  __shared__ int base[8];
  const int t = threadIdx.x;
  if (t < 8) cnt[t] = 0;
  __syncthreads();
  const int s = sel[t];
  atomicAdd(&cnt[s], 1);
  __syncthreads();
  if (t == 0){
    int a = 0;
    for (int o = 0; o < 8; ++o){ offsets[o] = a; base[o] = a; a += cnt[o]; }
    offsets[8] = a;
    int nt = 0;
    for (int o = 0; o < 8; ++o)
      for (int mb = offsets[o]; mb < offsets[o] + cnt[o]; mb += 64){
        tlist[1 + 2*nt] = o; tlist[2 + 2*nt] = mb; ++nt;
      }
    tlist[0] = nt;
  }
  __syncthreads();
  const int pos = atomicAdd(&base[s], 1);
  order[pos] = t;   // permutation within an expert is nondeterministic; outputs don't depend on it
}

// ---------------- per-row output head: q = h2 @ awo + abo, softmax, argmax ----------------
__global__ __launch_bounds__(256)
void expert_out_kernel(const float* __restrict__ he2, const float* __restrict__ awo,
                       const float* __restrict__ abo,
                       const int* __restrict__ order, const int* __restrict__ offsets,
                       float* __restrict__ out)
{
  const int r = blockIdx.x;
  int o = 0;
#pragma unroll
  for (int i = 1; i < 8; ++i) if (offsets[i] <= r) o = i;
  const int t = threadIdx.x;
  const int a = t & 63, kg = t >> 6;
  const float* hrow = he2 + r * Hdim;
  const float* W = awo + o * Hdim * Aact;
  float acc = 0.f;
  const int k0 = kg * 256;
  for (int k = k0; k < k0 + 256; ++k) acc += hrow[k] * W[k * Aact + a];
  __shared__ float redm[4][64];
  redm[kg][a] = acc;
  __syncthreads();
  if (t < 64){
    float q = redm[0][a] + redm[1][a] + redm[2][a] + redm[3][a] + abo[o * Aact + a];
    float m = q;
#pragma unroll
    for (int off = 32; off; off >>= 1) m = fmaxf(m, __shfl_xor(m, off));
    float e = expf(q - m);
    float s = e;
#pragma unroll
    for (int off = 32; off; off >>= 1) s += __shfl_xor(s, off);
    const int b = order[r];
    out[OFF_ACT + b * Aact + a] = e / s;
    unsigned long long msk = __ballot(q == m);
    if (a == 0) out[OFF_SACT + b] = (float)__builtin_ctzll(msk);
  }
}

extern "C" void kernel_launch(void* const* d_in, const int* in_sizes, int n_in,
                              void* d_out, int out_size, void* d_ws, size_t ws_size,
                              hipStream_t stream)
{
  (void)in_sizes; (void)n_in; (void)out_size; (void)ws_size;
  const float* state = (const float*)d_in[0];
  const float* ow1   = (const float*)d_in[1];
  const float* ob1   = (const float*)d_in[2];
  const float* ow2   = (const float*)d_in[3];
  const float* ob2   = (const float*)d_in[4];
  const float* aw1   = (const float*)d_in[5];
  const float* ab1   = (const float*)d_in[6];
  const float* awh   = (const float*)d_in[7];
  const float* abh   = (const float*)d_in[8];
  const float* awo   = (const float*)d_in[9];
  const float* abo   = (const float*)d_in[10];
  const float* tw1   = (const float*)d_in[11];
  const float* tb1   = (const float*)d_in[12];
  const float* tw2   = (const float*)d_in[13];
  const float* tb2   = (const float*)d_in[14];
  float* out = (float*)d_out;

  float* h1 = (float*)d_ws;                                 // dense opt hidden (fp32)
  float* h2 = h1 + (long long)Bsz * Hdim;                   // dense term hidden -> L2 out (fp32)
  unsigned short* sthi = (unsigned short*)(h2 + (long long)Bsz * Hdim);  // state hi [1024][512]
  unsigned short* stlo = sthi + (long long)Bsz * Din;
  unsigned short* h1hi = stlo + (long long)Bsz * Din;       // L1 out hi [1024][1024]
  unsigned short* h1lo = h1hi + (long long)Bsz * Hdim;
  int* sel     = (int*)(h1lo + (long long)Bsz * Hdim);
  int* order   = sel + Bsz;
  int* offsets = order + Bsz;
  int* tlist   = offsets + 9;           // [ntiles | (expert,mbase) * MAXT]

  // 1. state -> hi/lo bf16
  convert_state<<<dim3(512), 256, 0, stream>>>(state, sthi, stlo);
  // 2. dense pair: h1 = relu(st @ ow1 + ob1), h2 = relu(st @ tw1 + tb1)   [bf16x3 MFMA]
  mfma_gemm<true, false, false><<<dim3(16, 16, 2), 256, 0, stream>>>(
      sthi, stlo, Din, ow1, tw1, 0, ob1, tb1, 0, h1, h2, nullptr, nullptr,
      Hdim, Din, nullptr, nullptr, nullptr);
  // 3. heads: opt softmax/argmax, gumbel categorical sel, termination sigmoid
  head_kernel<<<dim3(Bsz), 256, 0, stream>>>(h1, h2, ow2, ob2, tw2, tb2, out, sel);
  // 4. bucket samples by expert + tile list
  route_kernel<<<dim3(1), 1024, 0, stream>>>(sel, order, offsets, tlist);
  // 5. expert L1 (gather state rows): h1hi/lo[r] = split(relu(state[order[r]] @ aw1[o] + ab1[o]))
  mfma_gemm<false, true, true><<<dim3(MAXT, 16), 256, 0, stream>>>(
      sthi, stlo, Din, aw1, nullptr, (long long)Din*Hdim, ab1, nullptr, Hdim,
      nullptr, nullptr, h1hi, h1lo, Hdim, Din, order, offsets, tlist);
  // 6. expert L2: h2[r] = relu(h1[r] @ awh[o,0] + abh[o,0])   [A already hi/lo]
  mfma_gemm<false, false, false><<<dim3(MAXT, 16), 256, 0, stream>>>(
      h1hi, h1lo, Hdim, awh, nullptr, (long long)Hdim*Hdim, abh, nullptr, Hdim,
      h2, nullptr, nullptr, nullptr, Hdim, Hdim, nullptr, offsets, tlist);
  // 7. output head: q, action softmax, selected action
  expert_out_kernel<<<dim3(Bsz), 256, 0, stream>>>(h2, awo, abo, order, offsets, out);
}